// Round 1
// baseline (547.725 us; speedup 1.0000x reference)
//
#include <hip/hip_runtime.h>

#define BATCH 32
#define CIN   64
#define COUT  64
#define NFFT  4096
#define MODES 1024
#define KOUT  2049   // N/2 + 1

// ---------------- fill kernels ----------------

// tw[h + n] = cas(pi*n/h) for h in {1,2,...,2048}, n in [0,h). tw[0] unused.
__global__ void fill_tw(float* __restrict__ tw) {
    int t = blockIdx.x * blockDim.x + threadIdx.x;
    if (t >= NFFT) return;
    if (t == 0) { tw[0] = 1.0f; return; }
    int h = 1 << (31 - __clz(t));
    int n = t - h;
    float ang = 3.14159265358979323846f * (float)n / (float)h;
    tw[t] = cosf(ang) + sinf(ang);
}

// c2[k*KOUT + n] = cas(2*pi*(k*n mod KOUT)/KOUT) / KOUT
__global__ void fill_c2(float* __restrict__ c2) {
    int idx = blockIdx.x * blockDim.x + threadIdx.x;
    if (idx >= MODES * KOUT) return;
    int k = idx / KOUT;
    int n = idx - k * KOUT;
    int m = (k * n) % KOUT;   // fits in int32 (max ~2.1M)
    float ang = 6.28318530717958647692f * (float)m / (float)KOUT;
    c2[idx] = (cosf(ang) + sinf(ang)) * (1.0f / (float)KOUT);
}

// ---------------- stage 1: recursive "FHT" (Stockham radix-2 DIT) ----------------
// Reproduces exactly the reference recursion:
//   out[k]       = E[k] + cas(2*pi*k/L')*O[k]
//   out[k+L'/2]  = E[k] - cas(2*pi*k/L')*O[k]
// Stockham layout: W_s[k*r + g] = T_L(g)[k], r = N/L. Natural-order in and out.
__global__ __launch_bounds__(256) void fht_kernel(const float* __restrict__ x,
                                                  const float* __restrict__ tw,
                                                  float* __restrict__ xh) {
    __shared__ float bufA[NFFT];
    __shared__ float bufB[NFFT];
    const int row = blockIdx.x;              // b*CIN + i, 0..2047
    const float* xr = x + (size_t)row * NFFT;
    for (int j = threadIdx.x; j < NFFT; j += 256) bufA[j] = xr[j];
    __syncthreads();

    float* src = bufA;
    float* dst = bufB;
    for (int s = 0; s < 12; ++s) {
        const int L = 1 << s;
        const int shift = 11 - s;            // rp = 1<<shift = N/(2L)
        const int rp = 1 << shift;
        for (int j = threadIdx.x; j < 2048; j += 256) {
            int k = j >> shift;              // k in [0, L)
            int base = j + (k << shift);     // = 2*k*rp + g
            float e = src[base];
            float o = src[base + rp];
            float t = tw[L + k];             // cas(pi*k/L) = cas(2*pi*k/(2L))
            float p = t * o;
            dst[j]        = e + p;
            dst[j + 2048] = e - p;
        }
        __syncthreads();
        float* tmp = src; src = dst; dst = tmp;
    }
    // after 12 stages result is back in bufA (src); keep only first MODES outputs
    for (int j = threadIdx.x; j < MODES; j += 256)
        xh[(size_t)row * MODES + j] = src[j];
}

// ---------------- stage 2: channel mix ----------------
// Y[b,o,k] = 0.5 * sum_i [ Xh[b,i,k]*(W[i,o,k]+W[63-i,o,k]) + Xh[31-b,i,k]*(W[i,o,k]-W[63-i,o,k]) ]
// Pair (i, 63-i) and (b, 31-b) to reuse loads.
__global__ __launch_bounds__(256) void mix_kernel(const float* __restrict__ xh,
                                                  const float* __restrict__ w,
                                                  float* __restrict__ y) {
    const int kt = blockIdx.x;               // 0..15 (k tiles of 64)
    const int b  = blockIdx.y;               // 0..15 -> pair (b, 31-b)
    const int rb = (BATCH - 1) - b;
    const int kl = threadIdx.x & 63;
    const int og = threadIdx.x >> 6;         // 0..3 (16 o's each)
    const int k  = kt * 64 + kl;

    float accb[16], accr[16];
#pragma unroll
    for (int j = 0; j < 16; ++j) { accb[j] = 0.0f; accr[j] = 0.0f; }

    for (int i = 0; i < 32; ++i) {
        const int mi = 63 - i;
        float xai = xh[(size_t)(b  * CIN + i ) * MODES + k];
        float xam = xh[(size_t)(b  * CIN + mi) * MODES + k];
        float xbi = xh[(size_t)(rb * CIN + i ) * MODES + k];
        float xbm = xh[(size_t)(rb * CIN + mi) * MODES + k];
        float sa = xai + xam;   // pairs with wp for acc_b
        float da = xai - xam;   // pairs with wm for acc_rb
        float sb = xbi + xbm;
        float db = xbi - xbm;
#pragma unroll
        for (int j = 0; j < 16; ++j) {
            int o = og * 16 + j;
            float w1 = w[(size_t)(i  * COUT + o) * MODES + k];
            float w2 = w[(size_t)(mi * COUT + o) * MODES + k];
            float wp = w1 + w2;
            float wm = w1 - w2;
            accb[j] = fmaf(sa, wp, fmaf(db, wm, accb[j]));
            accr[j] = fmaf(sb, wp, fmaf(da, wm, accr[j]));
        }
    }
#pragma unroll
    for (int j = 0; j < 16; ++j) {
        int o = og * 16 + j;
        y[(size_t)(b  * COUT + o) * MODES + k] = 0.5f * accb[j];
        y[(size_t)(rb * COUT + o) * MODES + k] = 0.5f * accr[j];
    }
}

// ---------------- stage 3: iDHT as GEMM ----------------
// out[r, n] = sum_{k<1024} Y[r, k] * C2[k, n],  r in [0,2048), n in [0,2049)
#define BM 64
#define BN 64
#define BK 32

__global__ __launch_bounds__(256) void idht_gemm(const float* __restrict__ yv,
                                                 const float* __restrict__ c2,
                                                 float* __restrict__ out) {
    __shared__ __align__(16) float at[BM][36];   // [m][k], stride 36 dwords (16B-aligned rows, 2-way banks)
    __shared__ __align__(16) float bt[BK][BN];   // [k][n]

    const int rbase = blockIdx.x * BM;           // 32 tiles, always full
    const int nbase = blockIdx.y * BN;           // 33 tiles, last has 1 valid col
    const int tx = threadIdx.x & 15;             // col group: cols tx*4..tx*4+3
    const int ty = threadIdx.x >> 4;             // row group: rows ty*4..ty*4+3

    float acc[4][4];
#pragma unroll
    for (int i = 0; i < 4; ++i)
#pragma unroll
        for (int j = 0; j < 4; ++j) acc[i][j] = 0.0f;

    for (int k0 = 0; k0 < MODES; k0 += BK) {
        for (int l = threadIdx.x; l < BM * BK; l += 256) {
            int m  = l >> 5;
            int kk = l & 31;
            at[m][kk] = yv[(size_t)(rbase + m) * MODES + k0 + kk];
        }
        for (int l = threadIdx.x; l < BK * BN; l += 256) {
            int kk = l >> 6;
            int n  = l & 63;
            int col = nbase + n;
            bt[kk][n] = (col < KOUT) ? c2[(size_t)(k0 + kk) * KOUT + col] : 0.0f;
        }
        __syncthreads();

#pragma unroll
        for (int kg = 0; kg < BK / 4; ++kg) {
            float a[4][4];   // [row i][k lane q]
            *(float4*)a[0] = *(const float4*)&at[ty * 4 + 0][kg * 4];
            *(float4*)a[1] = *(const float4*)&at[ty * 4 + 1][kg * 4];
            *(float4*)a[2] = *(const float4*)&at[ty * 4 + 2][kg * 4];
            *(float4*)a[3] = *(const float4*)&at[ty * 4 + 3][kg * 4];
#pragma unroll
            for (int q = 0; q < 4; ++q) {
                float bv[4];
                *(float4*)bv = *(const float4*)&bt[kg * 4 + q][tx * 4];
#pragma unroll
                for (int i = 0; i < 4; ++i)
#pragma unroll
                    for (int j = 0; j < 4; ++j)
                        acc[i][j] = fmaf(a[i][q], bv[j], acc[i][j]);
            }
        }
        __syncthreads();
    }

#pragma unroll
    for (int i = 0; i < 4; ++i) {
        int r = rbase + ty * 4 + i;
#pragma unroll
        for (int j = 0; j < 4; ++j) {
            int col = nbase + tx * 4 + j;
            if (col < KOUT) out[(size_t)r * KOUT + col] = acc[i][j];
        }
    }
}

// ---------------- launch ----------------
extern "C" void kernel_launch(void* const* d_in, const int* in_sizes, int n_in,
                              void* d_out, int out_size, void* d_ws, size_t ws_size,
                              hipStream_t stream) {
    const float* x = (const float*)d_in[0];     // (32, 64, 4096)
    const float* w = (const float*)d_in[1];     // (64, 64, 1024)
    float* out = (float*)d_out;                 // (32, 64, 2049)

    float* ws = (float*)d_ws;
    float* tw = ws;                                   // 4096
    float* c2 = tw + NFFT;                            // 1024*2049
    float* xh = c2 + (size_t)MODES * KOUT;            // 2048*1024
    float* y  = xh + (size_t)(BATCH * CIN) * MODES;   // 2048*1024

    fill_tw<<<NFFT / 256, 256, 0, stream>>>(tw);
    fill_c2<<<(MODES * KOUT + 255) / 256, 256, 0, stream>>>(c2);
    fht_kernel<<<BATCH * CIN, 256, 0, stream>>>(x, tw, xh);
    mix_kernel<<<dim3(16, 16), 256, 0, stream>>>(xh, w, y);
    idht_gemm<<<dim3((BATCH * COUT) / BM, (KOUT + BN - 1) / BN), 256, 0, stream>>>(y, c2, out);
}

// Round 2
// 249.666 us; speedup vs baseline: 2.1938x; 2.1938x over previous
//
#include <hip/hip_runtime.h>
#include <hip/hip_bf16.h>

#define BATCH 32
#define CIN   64
#define COUT  64
#define NFFT  4096
#define MODES 1024
#define KOUT  2049   // N/2 + 1
#define NPAD  2176   // KOUT padded up to multiple of 64

typedef __bf16 bf16x8 __attribute__((ext_vector_type(8)));
typedef float  f32x4  __attribute__((ext_vector_type(4)));

#define AS1 __attribute__((address_space(1)))
#define AS3 __attribute__((address_space(3)))

static __device__ __forceinline__ void gl_lds16(const void* g, void* l) {
    __builtin_amdgcn_global_load_lds((const AS1 void*)g, (AS3 void*)l, 16, 0, 0);
}

// ---------------- fill kernels ----------------

// tw[h + n] = cas(pi*n/h) for h in {1,2,...,2048}, n in [0,h). tw[0] unused.
__global__ void fill_tw(float* __restrict__ tw) {
    int t = blockIdx.x * blockDim.x + threadIdx.x;
    if (t >= NFFT) return;
    if (t == 0) { tw[0] = 1.0f; return; }
    int h = 1 << (31 - __clz(t));
    int n = t - h;
    float ang = 3.14159265358979323846f * (float)n / (float)h;
    tw[t] = cosf(ang) + sinf(ang);
}

// c2t[n*1024 + k] = cas(2*pi*(k*n mod KOUT)/KOUT)/KOUT, transposed+padded, split hi/lo bf16
__global__ void fill_c2t(__hip_bfloat16* __restrict__ hi, __hip_bfloat16* __restrict__ lo) {
    int idx = blockIdx.x * blockDim.x + threadIdx.x;
    if (idx >= NPAD * MODES) return;
    int n = idx >> 10;
    int k = idx & 1023;
    float v = 0.0f;
    if (n < KOUT) {
        int m = (k * n) % KOUT;   // max ~2.1M, fits int32
        float ang = 6.28318530717958647692f * (float)m / (float)KOUT;
        v = (cosf(ang) + sinf(ang)) * (1.0f / (float)KOUT);
    }
    __hip_bfloat16 h = __float2bfloat16(v);
    hi[idx] = h;
    lo[idx] = __float2bfloat16(v - __bfloat162float(h));
}

// ---------------- stage 1: recursive "FHT" (Stockham radix-2 DIT) ----------------
__global__ __launch_bounds__(256) void fht_kernel(const float* __restrict__ x,
                                                  const float* __restrict__ tw,
                                                  float* __restrict__ xh) {
    __shared__ float bufA[NFFT];
    __shared__ float bufB[NFFT];
    const int row = blockIdx.x;              // b*CIN + i, 0..2047
    const float* xr = x + (size_t)row * NFFT;
    for (int j = threadIdx.x; j < NFFT; j += 256) bufA[j] = xr[j];
    __syncthreads();

    float* src = bufA;
    float* dst = bufB;
    for (int s = 0; s < 12; ++s) {
        const int L = 1 << s;
        const int shift = 11 - s;
        const int rp = 1 << shift;
        for (int j = threadIdx.x; j < 2048; j += 256) {
            int k = j >> shift;
            int base = j + (k << shift);
            float e = src[base];
            float o = src[base + rp];
            float t = tw[L + k];
            float p = t * o;
            dst[j]        = e + p;
            dst[j + 2048] = e - p;
        }
        __syncthreads();
        float* tmp = src; src = dst; dst = tmp;
    }
    for (int j = threadIdx.x; j < MODES; j += 256)
        xh[(size_t)row * MODES + j] = src[j];
}

// ---------------- stage 2: channel mix -> Y as split bf16 hi/lo ----------------
__global__ __launch_bounds__(256) void mix_kernel(const float* __restrict__ xh,
                                                  const float* __restrict__ w,
                                                  __hip_bfloat16* __restrict__ y_hi,
                                                  __hip_bfloat16* __restrict__ y_lo) {
    const int kt = blockIdx.x;               // 0..15
    const int b  = blockIdx.y;               // 0..15 -> pair (b, 31-b)
    const int rb = (BATCH - 1) - b;
    const int kl = threadIdx.x & 63;
    const int og = threadIdx.x >> 6;         // 0..3
    const int k  = kt * 64 + kl;

    float accb[16], accr[16];
#pragma unroll
    for (int j = 0; j < 16; ++j) { accb[j] = 0.0f; accr[j] = 0.0f; }

    for (int i = 0; i < 32; ++i) {
        const int mi = 63 - i;
        float xai = xh[(size_t)(b  * CIN + i ) * MODES + k];
        float xam = xh[(size_t)(b  * CIN + mi) * MODES + k];
        float xbi = xh[(size_t)(rb * CIN + i ) * MODES + k];
        float xbm = xh[(size_t)(rb * CIN + mi) * MODES + k];
        float sa = xai + xam;
        float da = xai - xam;
        float sb = xbi + xbm;
        float db = xbi - xbm;
#pragma unroll
        for (int j = 0; j < 16; ++j) {
            int o = og * 16 + j;
            float w1 = w[(size_t)(i  * COUT + o) * MODES + k];
            float w2 = w[(size_t)(mi * COUT + o) * MODES + k];
            float wp = w1 + w2;
            float wm = w1 - w2;
            accb[j] = fmaf(sa, wp, fmaf(db, wm, accb[j]));
            accr[j] = fmaf(sb, wp, fmaf(da, wm, accr[j]));
        }
    }
#pragma unroll
    for (int j = 0; j < 16; ++j) {
        int o = og * 16 + j;
        float vb = 0.5f * accb[j];
        float vr = 0.5f * accr[j];
        size_t ib = (size_t)(b  * COUT + o) * MODES + k;
        size_t ir = (size_t)(rb * COUT + o) * MODES + k;
        __hip_bfloat16 hb = __float2bfloat16(vb);
        y_hi[ib] = hb;
        y_lo[ib] = __float2bfloat16(vb - __bfloat162float(hb));
        __hip_bfloat16 hr = __float2bfloat16(vr);
        y_hi[ir] = hr;
        y_lo[ir] = __float2bfloat16(vr - __bfloat162float(hr));
    }
}

// ---------------- stage 3: iDHT as split-bf16 MFMA GEMM ----------------
// out[r,n] = sum_k Y[r,k]*C2[k,n]; A=Y (2048x1024 row-major), B=C2T (n-major [NPAD][1024])
// Tile 128x64, BK=32, 4 waves: wave (wm,wn) covers rows wm*64+0..63, cols wn*32+0..31.
__global__ __launch_bounds__(256) void idht_mfma(const __hip_bfloat16* __restrict__ yh,
                                                 const __hip_bfloat16* __restrict__ yl,
                                                 const __hip_bfloat16* __restrict__ ch,
                                                 const __hip_bfloat16* __restrict__ cl,
                                                 float* __restrict__ out) {
    __shared__ __hip_bfloat16 sa_h[128 * 32];   // [m][k] 8KB
    __shared__ __hip_bfloat16 sa_l[128 * 32];
    __shared__ __hip_bfloat16 sb_h[64 * 32];    // [n][k] 4KB
    __shared__ __hip_bfloat16 sb_l[64 * 32];

    const int tid  = threadIdx.x;
    const int lane = tid & 63;
    const int wave = tid >> 6;
    const int wm = wave & 1;
    const int wn = wave >> 1;
    const int rbase = blockIdx.x * 128;
    const int nbase = blockIdx.y * 64;

    f32x4 acc[4][2];
#pragma unroll
    for (int mt = 0; mt < 4; ++mt)
#pragma unroll
        for (int nt = 0; nt < 2; ++nt) acc[mt][nt] = (f32x4){0.f, 0.f, 0.f, 0.f};

    const int srow = tid >> 2;            // 0..63: staging row within round
    const int sq   = (tid & 3) * 16;      // byte offset within 64B row-chunk
    const int ldso = wave * 1024;         // LDS byte base for this wave's chunk

    for (int k0 = 0; k0 < MODES; k0 += 32) {
        const char* ga_h = (const char*)yh + ((size_t)rbase * MODES + k0) * 2;
        const char* ga_l = (const char*)yl + ((size_t)rbase * MODES + k0) * 2;
        const char* gb_h = (const char*)ch + ((size_t)nbase * MODES + k0) * 2;
        const char* gb_l = (const char*)cl + ((size_t)nbase * MODES + k0) * 2;

        // A tiles: 128 rows x 64B -> 2 rounds of 256x16B each
        gl_lds16(ga_h + (size_t)srow * 2048 + sq,        (char*)sa_h + ldso);
        gl_lds16(ga_h + (size_t)(64 + srow) * 2048 + sq, (char*)sa_h + 4096 + ldso);
        gl_lds16(ga_l + (size_t)srow * 2048 + sq,        (char*)sa_l + ldso);
        gl_lds16(ga_l + (size_t)(64 + srow) * 2048 + sq, (char*)sa_l + 4096 + ldso);
        // B tiles: 64 rows x 64B -> 1 round each
        gl_lds16(gb_h + (size_t)srow * 2048 + sq, (char*)sb_h + ldso);
        gl_lds16(gb_l + (size_t)srow * 2048 + sq, (char*)sb_l + ldso);
        __syncthreads();

        const int fm = lane & 15;
        const int fk = (lane >> 4) * 8;
        bf16x8 ah[4], al[4], bh[2], bl[2];
#pragma unroll
        for (int mt = 0; mt < 4; ++mt) {
            int row = wm * 64 + mt * 16 + fm;
            ah[mt] = *(const bf16x8*)&sa_h[row * 32 + fk];
            al[mt] = *(const bf16x8*)&sa_l[row * 32 + fk];
        }
#pragma unroll
        for (int nt = 0; nt < 2; ++nt) {
            int col = wn * 32 + nt * 16 + fm;
            bh[nt] = *(const bf16x8*)&sb_h[col * 32 + fk];
            bl[nt] = *(const bf16x8*)&sb_l[col * 32 + fk];
        }
#pragma unroll
        for (int mt = 0; mt < 4; ++mt)
#pragma unroll
            for (int nt = 0; nt < 2; ++nt) {
                acc[mt][nt] = __builtin_amdgcn_mfma_f32_16x16x32_bf16(ah[mt], bh[nt], acc[mt][nt], 0, 0, 0);
                acc[mt][nt] = __builtin_amdgcn_mfma_f32_16x16x32_bf16(ah[mt], bl[nt], acc[mt][nt], 0, 0, 0);
                acc[mt][nt] = __builtin_amdgcn_mfma_f32_16x16x32_bf16(al[mt], bh[nt], acc[mt][nt], 0, 0, 0);
            }
        __syncthreads();
    }

    // epilogue: C/D layout col=lane&15, row=(lane>>4)*4+reg
#pragma unroll
    for (int mt = 0; mt < 4; ++mt) {
        int row = rbase + wm * 64 + mt * 16 + (lane >> 4) * 4;
#pragma unroll
        for (int nt = 0; nt < 2; ++nt) {
            int col = nbase + wn * 32 + nt * 16 + (lane & 15);
            if (col < KOUT) {
#pragma unroll
                for (int r = 0; r < 4; ++r)
                    out[(size_t)(row + r) * KOUT + col] = acc[mt][nt][r];
            }
        }
    }
}

// ---------------- launch ----------------
extern "C" void kernel_launch(void* const* d_in, const int* in_sizes, int n_in,
                              void* d_out, int out_size, void* d_ws, size_t ws_size,
                              hipStream_t stream) {
    const float* x = (const float*)d_in[0];     // (32, 64, 4096)
    const float* w = (const float*)d_in[1];     // (64, 64, 1024)
    float* out = (float*)d_out;                 // (32, 64, 2049)

    float* tw = (float*)d_ws;                                  // 4096 f32
    float* xh = tw + NFFT;                                     // 2048*1024 f32
    __hip_bfloat16* y_hi = (__hip_bfloat16*)(xh + (size_t)BATCH * CIN * MODES);
    __hip_bfloat16* y_lo = y_hi + (size_t)BATCH * COUT * MODES;
    __hip_bfloat16* c2h  = y_lo + (size_t)BATCH * COUT * MODES;
    __hip_bfloat16* c2l  = c2h + (size_t)NPAD * MODES;

    fill_tw<<<NFFT / 256, 256, 0, stream>>>(tw);
    fill_c2t<<<(NPAD * MODES + 255) / 256, 256, 0, stream>>>(c2h, c2l);
    fht_kernel<<<BATCH * CIN, 256, 0, stream>>>(x, tw, xh);
    mix_kernel<<<dim3(16, 16), 256, 0, stream>>>(xh, w, y_hi, y_lo);
    idht_mfma<<<dim3((BATCH * COUT) / 128, NPAD / 64), 256, 0, stream>>>(y_hi, y_lo, c2h, c2l, out);
}

// Round 3
// 186.105 us; speedup vs baseline: 2.9431x; 1.3415x over previous
//
#include <hip/hip_runtime.h>
#include <hip/hip_bf16.h>

#define BATCH 32
#define CIN   64
#define COUT  64
#define NFFT  4096
#define MODES 1024
#define KOUT  2049   // N/2 + 1
#define NPAD  2176   // KOUT padded up to multiple of 64

typedef __bf16 bf16x8 __attribute__((ext_vector_type(8)));
typedef float  f32x4  __attribute__((ext_vector_type(4)));

#define AS1 __attribute__((address_space(1)))
#define AS3 __attribute__((address_space(3)))

static __device__ __forceinline__ void gl_lds16(const void* g, void* l) {
    __builtin_amdgcn_global_load_lds((const AS1 void*)g, (AS3 void*)l, 16, 0, 0);
}

// ---------------- fill kernels ----------------

// tw[h + n] = cas(pi*n/h) for h in {1,2,...,2048}, n in [0,h). tw[0] unused.
__global__ void fill_tw(float* __restrict__ tw) {
    int t = blockIdx.x * blockDim.x + threadIdx.x;
    if (t >= NFFT) return;
    if (t == 0) { tw[0] = 1.0f; return; }
    int h = 1 << (31 - __clz(t));
    int n = t - h;
    float ang = 3.14159265358979323846f * (float)n / (float)h;
    tw[t] = cosf(ang) + sinf(ang);
}

// c2t[n*1024 + k] = cas(2*pi*(k*n mod KOUT)/KOUT)/KOUT, transposed+padded, split hi/lo bf16
__global__ void fill_c2t(__hip_bfloat16* __restrict__ hi, __hip_bfloat16* __restrict__ lo) {
    int idx = blockIdx.x * blockDim.x + threadIdx.x;
    if (idx >= NPAD * MODES) return;
    int n = idx >> 10;
    int k = idx & 1023;
    float v = 0.0f;
    if (n < KOUT) {
        int m = (k * n) % KOUT;   // max ~2.1M, fits int32
        float ang = 6.28318530717958647692f * (float)m / (float)KOUT;
        v = (cosf(ang) + sinf(ang)) * (1.0f / (float)KOUT);
    }
    __hip_bfloat16 h = __float2bfloat16(v);
    hi[idx] = h;
    lo[idx] = __float2bfloat16(v - __bfloat162float(h));
}

// ---------------- stage 1: recursive "FHT" (Stockham radix-2 DIT) ----------------
__global__ __launch_bounds__(256) void fht_kernel(const float* __restrict__ x,
                                                  const float* __restrict__ tw,
                                                  float* __restrict__ xh) {
    __shared__ float bufA[NFFT];
    __shared__ float bufB[NFFT];
    const int row = blockIdx.x;              // b*CIN + i, 0..2047
    const float* xr = x + (size_t)row * NFFT;
    for (int j = threadIdx.x; j < NFFT; j += 256) bufA[j] = xr[j];
    __syncthreads();

    float* src = bufA;
    float* dst = bufB;
    for (int s = 0; s < 12; ++s) {
        const int L = 1 << s;
        const int shift = 11 - s;
        const int rp = 1 << shift;
        for (int j = threadIdx.x; j < 2048; j += 256) {
            int k = j >> shift;
            int base = j + (k << shift);
            float e = src[base];
            float o = src[base + rp];
            float t = tw[L + k];
            float p = t * o;
            dst[j]        = e + p;
            dst[j + 2048] = e - p;
        }
        __syncthreads();
        float* tmp = src; src = dst; dst = tmp;
    }
    for (int j = threadIdx.x; j < MODES; j += 256)
        xh[(size_t)row * MODES + j] = src[j];
}

// ---------------- stage 2: channel mix -> Y as split bf16 hi/lo ----------------
// Thread tile: 4 k (float4) x 2 o x 2 b (pair b,31-b). Grid (kt=4, b=16, og=8).
// Y[b,o,k] = 0.5 * sum_i [ Xh[b,i,k]*(W[i,o,k]+W[63-i,o,k]) + Xh[31-b,i,k]*(W[i,o,k]-W[63-i,o,k]) ]
__global__ __launch_bounds__(256) void mix_kernel(const f32x4* __restrict__ xh,
                                                  const f32x4* __restrict__ w,
                                                  ushort4* __restrict__ y_hi,
                                                  ushort4* __restrict__ y_lo) {
    const int kl = threadIdx.x & 63;
    const int jg = threadIdx.x >> 6;          // 0..3
    const int k4 = blockIdx.x * 64 + kl;      // float4 index, 0..255
    const int b  = blockIdx.y;                // 0..15 -> pair (b, 31-b)
    const int rb = (BATCH - 1) - b;
    const int o0 = blockIdx.z * 8 + jg * 2;   // first of 2 o's

    f32x4 accb[2], accr[2];
#pragma unroll
    for (int j = 0; j < 2; ++j) {
        accb[j] = (f32x4){0.f, 0.f, 0.f, 0.f};
        accr[j] = (f32x4){0.f, 0.f, 0.f, 0.f};
    }

#pragma unroll 2
    for (int i = 0; i < 32; ++i) {
        const int mi = 63 - i;
        f32x4 xai = xh[(size_t)(b  * CIN + i ) * 256 + k4];
        f32x4 xam = xh[(size_t)(b  * CIN + mi) * 256 + k4];
        f32x4 xbi = xh[(size_t)(rb * CIN + i ) * 256 + k4];
        f32x4 xbm = xh[(size_t)(rb * CIN + mi) * 256 + k4];
        f32x4 w10 = w[(size_t)(i  * COUT + o0    ) * 256 + k4];
        f32x4 w20 = w[(size_t)(mi * COUT + o0    ) * 256 + k4];
        f32x4 w11 = w[(size_t)(i  * COUT + o0 + 1) * 256 + k4];
        f32x4 w21 = w[(size_t)(mi * COUT + o0 + 1) * 256 + k4];
        f32x4 sa = xai + xam;
        f32x4 da = xai - xam;
        f32x4 sb = xbi + xbm;
        f32x4 db = xbi - xbm;
        f32x4 wp0 = w10 + w20, wm0 = w10 - w20;
        f32x4 wp1 = w11 + w21, wm1 = w11 - w21;
        accb[0] += sa * wp0 + db * wm0;
        accr[0] += sb * wp0 + da * wm0;
        accb[1] += sa * wp1 + db * wm1;
        accr[1] += sb * wp1 + da * wm1;
    }

#pragma unroll
    for (int j = 0; j < 2; ++j) {
        const int o = o0 + j;
        const size_t ib = (size_t)(b  * COUT + o) * 256 + k4;
        const size_t ir = (size_t)(rb * COUT + o) * 256 + k4;
        f32x4 vb = accb[j] * 0.5f;
        f32x4 vr = accr[j] * 0.5f;
        ushort4 hb, lb, hr, lr;
        {
            float v0 = vb.x, v1 = vb.y, v2 = vb.z, v3 = vb.w;
            __hip_bfloat16 h0 = __float2bfloat16(v0), h1 = __float2bfloat16(v1),
                           h2 = __float2bfloat16(v2), h3 = __float2bfloat16(v3);
            hb = make_ushort4(*(unsigned short*)&h0, *(unsigned short*)&h1,
                              *(unsigned short*)&h2, *(unsigned short*)&h3);
            __hip_bfloat16 l0 = __float2bfloat16(v0 - __bfloat162float(h0));
            __hip_bfloat16 l1 = __float2bfloat16(v1 - __bfloat162float(h1));
            __hip_bfloat16 l2 = __float2bfloat16(v2 - __bfloat162float(h2));
            __hip_bfloat16 l3 = __float2bfloat16(v3 - __bfloat162float(h3));
            lb = make_ushort4(*(unsigned short*)&l0, *(unsigned short*)&l1,
                              *(unsigned short*)&l2, *(unsigned short*)&l3);
        }
        {
            float v0 = vr.x, v1 = vr.y, v2 = vr.z, v3 = vr.w;
            __hip_bfloat16 h0 = __float2bfloat16(v0), h1 = __float2bfloat16(v1),
                           h2 = __float2bfloat16(v2), h3 = __float2bfloat16(v3);
            hr = make_ushort4(*(unsigned short*)&h0, *(unsigned short*)&h1,
                              *(unsigned short*)&h2, *(unsigned short*)&h3);
            __hip_bfloat16 l0 = __float2bfloat16(v0 - __bfloat162float(h0));
            __hip_bfloat16 l1 = __float2bfloat16(v1 - __bfloat162float(h1));
            __hip_bfloat16 l2 = __float2bfloat16(v2 - __bfloat162float(h2));
            __hip_bfloat16 l3 = __float2bfloat16(v3 - __bfloat162float(h3));
            lr = make_ushort4(*(unsigned short*)&l0, *(unsigned short*)&l1,
                              *(unsigned short*)&l2, *(unsigned short*)&l3);
        }
        y_hi[ib] = hb;
        y_lo[ib] = lb;
        y_hi[ir] = hr;
        y_lo[ir] = lr;
    }
}

// ---------------- stage 3: iDHT as split-bf16 MFMA GEMM ----------------
// out[r,n] = sum_k Y[r,k]*C2[k,n]; A=Y (2048x1024 row-major), B=C2T (n-major [NPAD][1024])
// Tile 128x64, BK=32, 4 waves: wave (wm,wn) covers rows wm*64+0..63, cols wn*32+0..31.
__global__ __launch_bounds__(256) void idht_mfma(const __hip_bfloat16* __restrict__ yh,
                                                 const __hip_bfloat16* __restrict__ yl,
                                                 const __hip_bfloat16* __restrict__ ch,
                                                 const __hip_bfloat16* __restrict__ cl,
                                                 float* __restrict__ out) {
    __shared__ __hip_bfloat16 sa_h[128 * 32];   // [m][k] 8KB
    __shared__ __hip_bfloat16 sa_l[128 * 32];
    __shared__ __hip_bfloat16 sb_h[64 * 32];    // [n][k] 4KB
    __shared__ __hip_bfloat16 sb_l[64 * 32];

    const int tid  = threadIdx.x;
    const int lane = tid & 63;
    const int wave = tid >> 6;
    const int wm = wave & 1;
    const int wn = wave >> 1;
    const int rbase = blockIdx.x * 128;
    const int nbase = blockIdx.y * 64;

    f32x4 acc[4][2];
#pragma unroll
    for (int mt = 0; mt < 4; ++mt)
#pragma unroll
        for (int nt = 0; nt < 2; ++nt) acc[mt][nt] = (f32x4){0.f, 0.f, 0.f, 0.f};

    const int srow = tid >> 2;            // 0..63: staging row within round
    const int sq   = (tid & 3) * 16;      // byte offset within 64B row-chunk
    const int ldso = wave * 1024;         // LDS byte base for this wave's chunk

    for (int k0 = 0; k0 < MODES; k0 += 32) {
        const char* ga_h = (const char*)yh + ((size_t)rbase * MODES + k0) * 2;
        const char* ga_l = (const char*)yl + ((size_t)rbase * MODES + k0) * 2;
        const char* gb_h = (const char*)ch + ((size_t)nbase * MODES + k0) * 2;
        const char* gb_l = (const char*)cl + ((size_t)nbase * MODES + k0) * 2;

        // A tiles: 128 rows x 64B -> 2 rounds of 256x16B each
        gl_lds16(ga_h + (size_t)srow * 2048 + sq,        (char*)sa_h + ldso);
        gl_lds16(ga_h + (size_t)(64 + srow) * 2048 + sq, (char*)sa_h + 4096 + ldso);
        gl_lds16(ga_l + (size_t)srow * 2048 + sq,        (char*)sa_l + ldso);
        gl_lds16(ga_l + (size_t)(64 + srow) * 2048 + sq, (char*)sa_l + 4096 + ldso);
        // B tiles: 64 rows x 64B -> 1 round each
        gl_lds16(gb_h + (size_t)srow * 2048 + sq, (char*)sb_h + ldso);
        gl_lds16(gb_l + (size_t)srow * 2048 + sq, (char*)sb_l + ldso);
        __syncthreads();

        const int fm = lane & 15;
        const int fk = (lane >> 4) * 8;
        bf16x8 ah[4], al[4], bh[2], bl[2];
#pragma unroll
        for (int mt = 0; mt < 4; ++mt) {
            int row = wm * 64 + mt * 16 + fm;
            ah[mt] = *(const bf16x8*)&sa_h[row * 32 + fk];
            al[mt] = *(const bf16x8*)&sa_l[row * 32 + fk];
        }
#pragma unroll
        for (int nt = 0; nt < 2; ++nt) {
            int col = wn * 32 + nt * 16 + fm;
            bh[nt] = *(const bf16x8*)&sb_h[col * 32 + fk];
            bl[nt] = *(const bf16x8*)&sb_l[col * 32 + fk];
        }
#pragma unroll
        for (int mt = 0; mt < 4; ++mt)
#pragma unroll
            for (int nt = 0; nt < 2; ++nt) {
                acc[mt][nt] = __builtin_amdgcn_mfma_f32_16x16x32_bf16(ah[mt], bh[nt], acc[mt][nt], 0, 0, 0);
                acc[mt][nt] = __builtin_amdgcn_mfma_f32_16x16x32_bf16(ah[mt], bl[nt], acc[mt][nt], 0, 0, 0);
                acc[mt][nt] = __builtin_amdgcn_mfma_f32_16x16x32_bf16(al[mt], bh[nt], acc[mt][nt], 0, 0, 0);
            }
        __syncthreads();
    }

    // epilogue: C/D layout col=lane&15, row=(lane>>4)*4+reg
#pragma unroll
    for (int mt = 0; mt < 4; ++mt) {
        int row = rbase + wm * 64 + mt * 16 + (lane >> 4) * 4;
#pragma unroll
        for (int nt = 0; nt < 2; ++nt) {
            int col = nbase + wn * 32 + nt * 16 + (lane & 15);
            if (col < KOUT) {
#pragma unroll
                for (int r = 0; r < 4; ++r)
                    out[(size_t)(row + r) * KOUT + col] = acc[mt][nt][r];
            }
        }
    }
}

// ---------------- launch ----------------
extern "C" void kernel_launch(void* const* d_in, const int* in_sizes, int n_in,
                              void* d_out, int out_size, void* d_ws, size_t ws_size,
                              hipStream_t stream) {
    const float* x = (const float*)d_in[0];     // (32, 64, 4096)
    const float* w = (const float*)d_in[1];     // (64, 64, 1024)
    float* out = (float*)d_out;                 // (32, 64, 2049)

    float* tw = (float*)d_ws;                                  // 4096 f32
    float* xh = tw + NFFT;                                     // 2048*1024 f32
    __hip_bfloat16* y_hi = (__hip_bfloat16*)(xh + (size_t)BATCH * CIN * MODES);
    __hip_bfloat16* y_lo = y_hi + (size_t)BATCH * COUT * MODES;
    __hip_bfloat16* c2h  = y_lo + (size_t)BATCH * COUT * MODES;
    __hip_bfloat16* c2l  = c2h + (size_t)NPAD * MODES;

    fill_tw<<<NFFT / 256, 256, 0, stream>>>(tw);
    fill_c2t<<<(NPAD * MODES + 255) / 256, 256, 0, stream>>>(c2h, c2l);
    fht_kernel<<<BATCH * CIN, 256, 0, stream>>>(x, tw, xh);
    mix_kernel<<<dim3(4, 16, 8), 256, 0, stream>>>((const f32x4*)xh, (const f32x4*)w,
                                                   (ushort4*)y_hi, (ushort4*)y_lo);
    idht_mfma<<<dim3((BATCH * COUT) / 128, NPAD / 64), 256, 0, stream>>>(y_hi, y_lo, c2h, c2l, out);
}

// Round 4
// 170.355 us; speedup vs baseline: 3.2152x; 1.0925x over previous
//
#include <hip/hip_runtime.h>
#include <hip/hip_bf16.h>

#define BATCH 32
#define CIN   64
#define COUT  64
#define NFFT  4096
#define MODES 1024
#define KOUT  2049   // N/2 + 1
#define NPAD  2176   // KOUT padded up to multiple of 64

typedef __bf16 bf16x8 __attribute__((ext_vector_type(8)));
typedef float  f32x4  __attribute__((ext_vector_type(4)));

#define AS1 __attribute__((address_space(1)))
#define AS3 __attribute__((address_space(3)))

static __device__ __forceinline__ void gl_lds16(const void* g, void* l) {
    __builtin_amdgcn_global_load_lds((const AS1 void*)g, (AS3 void*)l, 16, 0, 0);
}

// radix-4 butterfly helper (two fused radix-2 stages of the reference recursion)
static __device__ __forceinline__ void bfly4(float eA, float eB, float oA, float oB,
                                             float t, float c0, float c1,
                                             float& w0, float& w1, float& w2, float& w3) {
    float PA = fmaf(t, oA, eA), MA = fmaf(-t, oA, eA);
    float PB = fmaf(t, oB, eB), MB = fmaf(-t, oB, eB);
    w0 = fmaf(c0, PB, PA);
    w2 = fmaf(-c0, PB, PA);
    w1 = fmaf(c1, MB, MA);
    w3 = fmaf(-c1, MB, MA);
}

// ---------------- fill kernels ----------------

// tw[h + n] = cas(pi*n/h) for h in {1,2,...,2048}, n in [0,h). tw[0] unused.
__global__ void fill_tw(float* __restrict__ tw) {
    int t = blockIdx.x * blockDim.x + threadIdx.x;
    if (t >= NFFT) return;
    if (t == 0) { tw[0] = 1.0f; return; }
    int h = 1 << (31 - __clz(t));
    int n = t - h;
    float ang = 3.14159265358979323846f * (float)n / (float)h;
    tw[t] = cosf(ang) + sinf(ang);
}

// c2t[n*1024 + k] = cas(2*pi*(k*n mod KOUT)/KOUT)/KOUT, transposed+padded, split hi/lo bf16
__global__ void fill_c2t(__hip_bfloat16* __restrict__ hi, __hip_bfloat16* __restrict__ lo) {
    int idx = blockIdx.x * blockDim.x + threadIdx.x;
    if (idx >= NPAD * MODES) return;
    int n = idx >> 10;
    int k = idx & 1023;
    float v = 0.0f;
    if (n < KOUT) {
        int m = (k * n) % KOUT;   // max ~2.1M, fits int32
        float ang = 6.28318530717958647692f * (float)m / (float)KOUT;
        v = (cosf(ang) + sinf(ang)) * (1.0f / (float)KOUT);
    }
    __hip_bfloat16 h = __float2bfloat16(v);
    hi[idx] = h;
    lo[idx] = __float2bfloat16(v - __bfloat162float(h));
}

// ---------------- stage 1: recursive "FHT", radix-4 (2 stages/pass, 6 passes) ----------------
// Unit u (0..1023) of pass p (s=2p, shift=11-s, hq=2^(shift-1), L=2^s):
//   kap=u>>(shift-1), gp=u&(hq-1), b0=(kap<<(shift+1))+gp
//   reads src[b0 + c*hq], c=0..3; twiddles tw[L+kap], tw[2L+kap], tw[3L+kap]
//   writes dst[u], dst[u+1024], dst[u+2048], dst[u+3072]
__global__ __launch_bounds__(256) void fht_kernel(const float* __restrict__ x,
                                                  const float* __restrict__ tw,
                                                  float* __restrict__ xh) {
    __shared__ __align__(16) float bufA[NFFT];
    __shared__ __align__(16) float bufB[NFFT];
    const int tid = threadIdx.x;
    const int row = blockIdx.x;
    const float4* xr = (const float4*)(x + (size_t)row * NFFT);
    float4* bA4 = (float4*)bufA;
#pragma unroll
    for (int j = 0; j < 4; ++j) bA4[tid + j * 256] = xr[tid + j * 256];
    __syncthreads();

    float* src = bufA;
    float* dst = bufB;

    // passes p=0..2 (hq = 1024, 256, 64): scalar units, conflict-free strides
#pragma unroll
    for (int p = 0; p < 3; ++p) {
        const int s = 2 * p;
        const int L = 1 << s;
        const int shift = 11 - s;
        const int hq = 1 << (shift - 1);
#pragma unroll
        for (int q = 0; q < 4; ++q) {
            const int u = tid + q * 256;
            const int kap = u >> (shift - 1);
            const int gp = u & (hq - 1);
            const int b0 = (kap << (shift + 1)) + gp;
            float eA = src[b0];
            float eB = src[b0 + hq];
            float oA = src[b0 + 2 * hq];
            float oB = src[b0 + 3 * hq];
            float t  = tw[L + kap], c0 = tw[2 * L + kap], c1 = tw[3 * L + kap];
            float w0, w1, w2, w3;
            bfly4(eA, eB, oA, oB, t, c0, c1, w0, w1, w2, w3);
            dst[u]        = w0;
            dst[u + 1024] = w1;
            dst[u + 2048] = w2;
            dst[u + 3072] = w3;
        }
        __syncthreads();
        float* tmp = src; src = dst; dst = tmp;
    }

    // passes p=3,4 (hq = 16, 4): 4 consecutive units/thread, float4 I/O, shared kap
#pragma unroll
    for (int p = 3; p < 5; ++p) {
        const int s = 2 * p;
        const int L = 1 << s;
        const int shift = 11 - s;
        const int hq = 1 << (shift - 1);
        const int u0 = 4 * tid;
        const int kap = u0 >> (shift - 1);          // same for units u0..u0+3
        const int gp = u0 & (hq - 1);
        const int b0 = (kap << (shift + 1)) + gp;
        float4 V0 = *(const float4*)(src + b0);
        float4 V1 = *(const float4*)(src + b0 + hq);
        float4 V2 = *(const float4*)(src + b0 + 2 * hq);
        float4 V3 = *(const float4*)(src + b0 + 3 * hq);
        float t  = tw[L + kap], c0 = tw[2 * L + kap], c1 = tw[3 * L + kap];
        float4 W0, W1, W2, W3;
        bfly4(V0.x, V1.x, V2.x, V3.x, t, c0, c1, W0.x, W1.x, W2.x, W3.x);
        bfly4(V0.y, V1.y, V2.y, V3.y, t, c0, c1, W0.y, W1.y, W2.y, W3.y);
        bfly4(V0.z, V1.z, V2.z, V3.z, t, c0, c1, W0.z, W1.z, W2.z, W3.z);
        bfly4(V0.w, V1.w, V2.w, V3.w, t, c0, c1, W0.w, W1.w, W2.w, W3.w);
        *(float4*)(dst + u0)        = W0;
        *(float4*)(dst + u0 + 1024) = W1;
        *(float4*)(dst + u0 + 2048) = W2;
        *(float4*)(dst + u0 + 3072) = W3;
        __syncthreads();
        float* tmp = src; src = dst; dst = tmp;
    }

    // pass p=5 (hq = 1, s=10, L=1024): per-unit contiguous reads, vector twiddles
    {
        const int u0 = 4 * tid;
        float4 R0 = *(const float4*)(src + 4 * u0);
        float4 R1 = *(const float4*)(src + 4 * u0 + 4);
        float4 R2 = *(const float4*)(src + 4 * u0 + 8);
        float4 R3 = *(const float4*)(src + 4 * u0 + 12);
        float4 T  = *(const float4*)(tw + 1024 + u0);
        float4 C0 = *(const float4*)(tw + 2048 + u0);
        float4 C1 = *(const float4*)(tw + 3072 + u0);
        float4 W0, W1, W2, W3;
        bfly4(R0.x, R0.y, R0.z, R0.w, T.x, C0.x, C1.x, W0.x, W1.x, W2.x, W3.x);
        bfly4(R1.x, R1.y, R1.z, R1.w, T.y, C0.y, C1.y, W0.y, W1.y, W2.y, W3.y);
        bfly4(R2.x, R2.y, R2.z, R2.w, T.z, C0.z, C1.z, W0.z, W1.z, W2.z, W3.z);
        bfly4(R3.x, R3.y, R3.z, R3.w, T.w, C0.w, C1.w, W0.w, W1.w, W2.w, W3.w);
        *(float4*)(dst + u0)        = W0;
        *(float4*)(dst + u0 + 1024) = W1;
        *(float4*)(dst + u0 + 2048) = W2;
        *(float4*)(dst + u0 + 3072) = W3;
        __syncthreads();
        float* tmp = src; src = dst; dst = tmp;
    }

    // keep first MODES outputs
    ((float4*)(xh + (size_t)row * MODES))[tid] = ((const float4*)src)[tid];
}

// ---------------- stage 2: channel mix -> Y as plain bf16 ----------------
// Thread tile: 4 k (float4) x 2 o x 2 b (pair b,31-b). Grid (kt=4, b=16, og=8).
__global__ __launch_bounds__(256) void mix_kernel(const f32x4* __restrict__ xh,
                                                  const f32x4* __restrict__ w,
                                                  ushort4* __restrict__ y_hi) {
    const int kl = threadIdx.x & 63;
    const int jg = threadIdx.x >> 6;          // 0..3
    const int k4 = blockIdx.x * 64 + kl;      // float4 index, 0..255
    const int b  = blockIdx.y;                // 0..15 -> pair (b, 31-b)
    const int rb = (BATCH - 1) - b;
    const int o0 = blockIdx.z * 8 + jg * 2;   // first of 2 o's

    f32x4 accb[2], accr[2];
#pragma unroll
    for (int j = 0; j < 2; ++j) {
        accb[j] = (f32x4){0.f, 0.f, 0.f, 0.f};
        accr[j] = (f32x4){0.f, 0.f, 0.f, 0.f};
    }

#pragma unroll 2
    for (int i = 0; i < 32; ++i) {
        const int mi = 63 - i;
        f32x4 xai = xh[(size_t)(b  * CIN + i ) * 256 + k4];
        f32x4 xam = xh[(size_t)(b  * CIN + mi) * 256 + k4];
        f32x4 xbi = xh[(size_t)(rb * CIN + i ) * 256 + k4];
        f32x4 xbm = xh[(size_t)(rb * CIN + mi) * 256 + k4];
        f32x4 w10 = w[(size_t)(i  * COUT + o0    ) * 256 + k4];
        f32x4 w20 = w[(size_t)(mi * COUT + o0    ) * 256 + k4];
        f32x4 w11 = w[(size_t)(i  * COUT + o0 + 1) * 256 + k4];
        f32x4 w21 = w[(size_t)(mi * COUT + o0 + 1) * 256 + k4];
        f32x4 sa = xai + xam;
        f32x4 da = xai - xam;
        f32x4 sb = xbi + xbm;
        f32x4 db = xbi - xbm;
        f32x4 wp0 = w10 + w20, wm0 = w10 - w20;
        f32x4 wp1 = w11 + w21, wm1 = w11 - w21;
        accb[0] += sa * wp0 + db * wm0;
        accr[0] += sb * wp0 + da * wm0;
        accb[1] += sa * wp1 + db * wm1;
        accr[1] += sb * wp1 + da * wm1;
    }

#pragma unroll
    for (int j = 0; j < 2; ++j) {
        const int o = o0 + j;
        const size_t ib = (size_t)(b  * COUT + o) * 256 + k4;
        const size_t ir = (size_t)(rb * COUT + o) * 256 + k4;
        f32x4 vb = accb[j] * 0.5f;
        f32x4 vr = accr[j] * 0.5f;
        __hip_bfloat16 b0 = __float2bfloat16(vb.x), b1 = __float2bfloat16(vb.y),
                       b2 = __float2bfloat16(vb.z), b3 = __float2bfloat16(vb.w);
        __hip_bfloat16 r0 = __float2bfloat16(vr.x), r1 = __float2bfloat16(vr.y),
                       r2 = __float2bfloat16(vr.z), r3 = __float2bfloat16(vr.w);
        y_hi[ib] = make_ushort4(*(unsigned short*)&b0, *(unsigned short*)&b1,
                                *(unsigned short*)&b2, *(unsigned short*)&b3);
        y_hi[ir] = make_ushort4(*(unsigned short*)&r0, *(unsigned short*)&r1,
                                *(unsigned short*)&r2, *(unsigned short*)&r3);
    }
}

// ---------------- stage 3: iDHT MFMA GEMM, fragment-ordered LDS ----------------
// out[r,n] = sum_k Y[r,k]*C2[k,n]; A=Y bf16 (2048x1024), B=C2T split hi/lo ([NPAD][1024])
// Tile 128x64, BK=32, 4 waves (wm,wn): wave covers rows wm*64..+63, cols wn*32..+31.
// LDS layout: 16-row "groups" of 1024B; lane l's slot (l*16) holds row (l&15), k-chunk (l>>4)
// -> ds_read_b128 at base+lane*16 is sequential (zero bank conflicts), fragment-ready.
__global__ __launch_bounds__(256) void idht_mfma(const __hip_bfloat16* __restrict__ yh,
                                                 const __hip_bfloat16* __restrict__ ch,
                                                 const __hip_bfloat16* __restrict__ cl,
                                                 float* __restrict__ out) {
    __shared__ __align__(16) char sa_h[8 * 1024];   // A: 8 groups (128 rows x 32 k)
    __shared__ __align__(16) char sb_h[4 * 1024];   // B hi: 4 groups (64 cols x 32 k)
    __shared__ __align__(16) char sb_l[4 * 1024];   // B lo

    const int tid  = threadIdx.x;
    const int lane = tid & 63;
    const int wave = tid >> 6;
    const int wm = wave & 1;
    const int wn = wave >> 1;
    const int rbase = blockIdx.x * 128;
    const int nbase = blockIdx.y * 64;

    const int lrow = (lane & 15) * 2048;   // global byte offset: row within group
    const int lchk = (lane >> 4) * 16;     // global byte offset: k-chunk

    f32x4 acc[4][2];
#pragma unroll
    for (int mt = 0; mt < 4; ++mt)
#pragma unroll
        for (int nt = 0; nt < 2; ++nt) acc[mt][nt] = (f32x4){0.f, 0.f, 0.f, 0.f};

    for (int k0 = 0; k0 < MODES; k0 += 32) {
        const char* ga  = (const char*)yh + (size_t)rbase * 2048 + k0 * 2;
        const char* gbh = (const char*)ch + (size_t)nbase * 2048 + k0 * 2;
        const char* gbl = (const char*)cl + (size_t)nbase * 2048 + k0 * 2;

        gl_lds16(ga  + (size_t)(wave * 16) * 2048 + lrow + lchk,       sa_h + wave * 1024);
        gl_lds16(ga  + (size_t)((wave + 4) * 16) * 2048 + lrow + lchk, sa_h + (wave + 4) * 1024);
        gl_lds16(gbh + (size_t)(wave * 16) * 2048 + lrow + lchk,       sb_h + wave * 1024);
        gl_lds16(gbl + (size_t)(wave * 16) * 2048 + lrow + lchk,       sb_l + wave * 1024);
        __syncthreads();

        bf16x8 a_[4], bh_[2], bl_[2];
#pragma unroll
        for (int mt = 0; mt < 4; ++mt)
            a_[mt] = *(const bf16x8*)(sa_h + (wm * 4 + mt) * 1024 + lane * 16);
#pragma unroll
        for (int nt = 0; nt < 2; ++nt) {
            bh_[nt] = *(const bf16x8*)(sb_h + (wn * 2 + nt) * 1024 + lane * 16);
            bl_[nt] = *(const bf16x8*)(sb_l + (wn * 2 + nt) * 1024 + lane * 16);
        }
#pragma unroll
        for (int mt = 0; mt < 4; ++mt)
#pragma unroll
            for (int nt = 0; nt < 2; ++nt) {
                acc[mt][nt] = __builtin_amdgcn_mfma_f32_16x16x32_bf16(a_[mt], bh_[nt], acc[mt][nt], 0, 0, 0);
                acc[mt][nt] = __builtin_amdgcn_mfma_f32_16x16x32_bf16(a_[mt], bl_[nt], acc[mt][nt], 0, 0, 0);
            }
        __syncthreads();
    }

    // epilogue: C/D layout col=lane&15, row=(lane>>4)*4+reg
#pragma unroll
    for (int mt = 0; mt < 4; ++mt) {
        int row = rbase + wm * 64 + mt * 16 + (lane >> 4) * 4;
#pragma unroll
        for (int nt = 0; nt < 2; ++nt) {
            int col = nbase + wn * 32 + nt * 16 + (lane & 15);
            if (col < KOUT) {
#pragma unroll
                for (int r = 0; r < 4; ++r)
                    out[(size_t)(row + r) * KOUT + col] = acc[mt][nt][r];
            }
        }
    }
}

// ---------------- launch ----------------
extern "C" void kernel_launch(void* const* d_in, const int* in_sizes, int n_in,
                              void* d_out, int out_size, void* d_ws, size_t ws_size,
                              hipStream_t stream) {
    const float* x = (const float*)d_in[0];     // (32, 64, 4096)
    const float* w = (const float*)d_in[1];     // (64, 64, 1024)
    float* out = (float*)d_out;                 // (32, 64, 2049)

    float* tw = (float*)d_ws;                                  // 4096 f32
    float* xh = tw + NFFT;                                     // 2048*1024 f32
    __hip_bfloat16* y_hi = (__hip_bfloat16*)(xh + (size_t)BATCH * CIN * MODES);
    __hip_bfloat16* c2h  = y_hi + (size_t)BATCH * COUT * MODES;
    __hip_bfloat16* c2l  = c2h + (size_t)NPAD * MODES;

    fill_tw<<<NFFT / 256, 256, 0, stream>>>(tw);
    fill_c2t<<<(NPAD * MODES + 255) / 256, 256, 0, stream>>>(c2h, c2l);
    fht_kernel<<<BATCH * CIN, 256, 0, stream>>>(x, tw, xh);
    mix_kernel<<<dim3(4, 16, 8), 256, 0, stream>>>((const f32x4*)xh, (const f32x4*)w,
                                                   (ushort4*)y_hi);
    idht_mfma<<<dim3((BATCH * COUT) / 128, NPAD / 64), 256, 0, stream>>>(y_hi, c2h, c2l, out);
}

// Round 5
// 164.601 us; speedup vs baseline: 3.3276x; 1.0350x over previous
//
#include <hip/hip_runtime.h>
#include <hip/hip_bf16.h>

#define BATCH 32
#define CIN   64
#define COUT  64
#define NFFT  4096
#define MODES 1024
#define KOUT  2049   // N/2 + 1
#define NPAD  2176   // KOUT padded up to multiple of 64

typedef __bf16 bf16x8 __attribute__((ext_vector_type(8)));
typedef float  f32x4  __attribute__((ext_vector_type(4)));

#define AS1 __attribute__((address_space(1)))
#define AS3 __attribute__((address_space(3)))

static __device__ __forceinline__ void gl_lds16(const void* g, void* l) {
    __builtin_amdgcn_global_load_lds((const AS1 void*)g, (AS3 void*)l, 16, 0, 0);
}

// radix-4 butterfly helper (two fused radix-2 stages of the reference recursion)
static __device__ __forceinline__ void bfly4(float eA, float eB, float oA, float oB,
                                             float t, float c0, float c1,
                                             float& w0, float& w1, float& w2, float& w3) {
    float PA = fmaf(t, oA, eA), MA = fmaf(-t, oA, eA);
    float PB = fmaf(t, oB, eB), MB = fmaf(-t, oB, eB);
    w0 = fmaf(c0, PB, PA);
    w2 = fmaf(-c0, PB, PA);
    w1 = fmaf(c1, MB, MA);
    w3 = fmaf(-c1, MB, MA);
}

// ---------------- fill kernels ----------------

// tw[h + n] = cas(pi*n/h) for h in {1,2,...,2048}, n in [0,h). tw[0] unused.
__global__ void fill_tw(float* __restrict__ tw) {
    int t = blockIdx.x * blockDim.x + threadIdx.x;
    if (t >= NFFT) return;
    if (t == 0) { tw[0] = 1.0f; return; }
    int h = 1 << (31 - __clz(t));
    int n = t - h;
    float ang = 3.14159265358979323846f * (float)n / (float)h;
    tw[t] = cosf(ang) + sinf(ang);
}

// c2t[n*1024 + k] = cas(2*pi*(k*n mod KOUT)/KOUT)/KOUT, transposed+padded, plain bf16
__global__ void fill_c2t(__hip_bfloat16* __restrict__ hi) {
    int idx = blockIdx.x * blockDim.x + threadIdx.x;
    if (idx >= NPAD * MODES) return;
    int n = idx >> 10;
    int k = idx & 1023;
    float v = 0.0f;
    if (n < KOUT) {
        int m = (k * n) % KOUT;   // max ~2.1M, fits int32
        float ang = 6.28318530717958647692f * (float)m / (float)KOUT;
        v = (cosf(ang) + sinf(ang)) * (1.0f / (float)KOUT);
    }
    hi[idx] = __float2bfloat16(v);
}

// ---------------- stage 1: recursive "FHT", radix-4 (2 stages/pass, 6 passes) ----------------
__global__ __launch_bounds__(256) void fht_kernel(const float* __restrict__ x,
                                                  const float* __restrict__ tw,
                                                  float* __restrict__ xh) {
    __shared__ __align__(16) float bufA[NFFT];
    __shared__ __align__(16) float bufB[NFFT];
    const int tid = threadIdx.x;
    const int row = blockIdx.x;
    const float4* xr = (const float4*)(x + (size_t)row * NFFT);
    float4* bA4 = (float4*)bufA;
#pragma unroll
    for (int j = 0; j < 4; ++j) bA4[tid + j * 256] = xr[tid + j * 256];
    __syncthreads();

    float* src = bufA;
    float* dst = bufB;

    // pass p=0 (hq=1024): all twiddles are cas(0)=cas(pi/2)=1 -> pure adds
    {
#pragma unroll
        for (int q = 0; q < 4; ++q) {
            const int u = tid + q * 256;
            float eA = src[u];
            float eB = src[u + 1024];
            float oA = src[u + 2048];
            float oB = src[u + 3072];
            float PA = eA + oA, MA = eA - oA;
            float PB = eB + oB, MB = eB - oB;
            dst[u]        = PA + PB;
            dst[u + 2048] = PA - PB;
            dst[u + 1024] = MA + MB;
            dst[u + 3072] = MA - MB;
        }
        __syncthreads();
        float* tmp = src; src = dst; dst = tmp;
    }

    // passes p=1,2 (hq=256,64): kap wave-uniform -> scalar twiddles
#pragma unroll
    for (int p = 1; p < 3; ++p) {
        const int s = 2 * p;
        const int L = 1 << s;
        const int shift = 11 - s;
        const int hq = 1 << (shift - 1);
#pragma unroll
        for (int q = 0; q < 4; ++q) {
            const int u = tid + q * 256;
            const int kap = __builtin_amdgcn_readfirstlane(u >> (shift - 1));
            const int gp = u & (hq - 1);
            const int b0 = (kap << (shift + 1)) + gp;
            float eA = src[b0];
            float eB = src[b0 + hq];
            float oA = src[b0 + 2 * hq];
            float oB = src[b0 + 3 * hq];
            float t  = tw[L + kap], c0 = tw[2 * L + kap], c1 = tw[3 * L + kap];
            float w0, w1, w2, w3;
            bfly4(eA, eB, oA, oB, t, c0, c1, w0, w1, w2, w3);
            dst[u]        = w0;
            dst[u + 1024] = w1;
            dst[u + 2048] = w2;
            dst[u + 3072] = w3;
        }
        __syncthreads();
        float* tmp = src; src = dst; dst = tmp;
    }

    // passes p=3,4 (hq=16,4): 4 consecutive units/thread, float4 I/O, shared kap
#pragma unroll
    for (int p = 3; p < 5; ++p) {
        const int s = 2 * p;
        const int L = 1 << s;
        const int shift = 11 - s;
        const int hq = 1 << (shift - 1);
        const int u0 = 4 * tid;
        const int kap = u0 >> (shift - 1);
        const int gp = u0 & (hq - 1);
        const int b0 = (kap << (shift + 1)) + gp;
        float4 V0 = *(const float4*)(src + b0);
        float4 V1 = *(const float4*)(src + b0 + hq);
        float4 V2 = *(const float4*)(src + b0 + 2 * hq);
        float4 V3 = *(const float4*)(src + b0 + 3 * hq);
        float t  = tw[L + kap], c0 = tw[2 * L + kap], c1 = tw[3 * L + kap];
        float4 W0, W1, W2, W3;
        bfly4(V0.x, V1.x, V2.x, V3.x, t, c0, c1, W0.x, W1.x, W2.x, W3.x);
        bfly4(V0.y, V1.y, V2.y, V3.y, t, c0, c1, W0.y, W1.y, W2.y, W3.y);
        bfly4(V0.z, V1.z, V2.z, V3.z, t, c0, c1, W0.z, W1.z, W2.z, W3.z);
        bfly4(V0.w, V1.w, V2.w, V3.w, t, c0, c1, W0.w, W1.w, W2.w, W3.w);
        *(float4*)(dst + u0)        = W0;
        *(float4*)(dst + u0 + 1024) = W1;
        *(float4*)(dst + u0 + 2048) = W2;
        *(float4*)(dst + u0 + 3072) = W3;
        __syncthreads();
        float* tmp = src; src = dst; dst = tmp;
    }

    // pass p=5 (hq=1): per-unit contiguous reads, vector twiddles
    {
        const int u0 = 4 * tid;
        float4 R0 = *(const float4*)(src + 4 * u0);
        float4 R1 = *(const float4*)(src + 4 * u0 + 4);
        float4 R2 = *(const float4*)(src + 4 * u0 + 8);
        float4 R3 = *(const float4*)(src + 4 * u0 + 12);
        float4 T  = *(const float4*)(tw + 1024 + u0);
        float4 C0 = *(const float4*)(tw + 2048 + u0);
        float4 C1 = *(const float4*)(tw + 3072 + u0);
        float4 W0, W1, W2, W3;
        bfly4(R0.x, R0.y, R0.z, R0.w, T.x, C0.x, C1.x, W0.x, W1.x, W2.x, W3.x);
        bfly4(R1.x, R1.y, R1.z, R1.w, T.y, C0.y, C1.y, W0.y, W1.y, W2.y, W3.y);
        bfly4(R2.x, R2.y, R2.z, R2.w, T.z, C0.z, C1.z, W0.z, W1.z, W2.z, W3.z);
        bfly4(R3.x, R3.y, R3.z, R3.w, T.w, C0.w, C1.w, W0.w, W1.w, W2.w, W3.w);
        *(float4*)(dst + u0)        = W0;
        *(float4*)(dst + u0 + 1024) = W1;
        *(float4*)(dst + u0 + 2048) = W2;
        *(float4*)(dst + u0 + 3072) = W3;
        __syncthreads();
        float* tmp = src; src = dst; dst = tmp;
    }

    ((float4*)(xh + (size_t)row * MODES))[tid] = ((const float4*)src)[tid];
}

// ---------------- stage 2: channel mix -> Y as plain bf16 ----------------
// Thread: 4 k (float4) x 1 o x 2 b (pair b,31-b). Grid (kt=4, b=16, oz=16).
__global__ __launch_bounds__(256) void mix_kernel(const f32x4* __restrict__ xh,
                                                  const f32x4* __restrict__ w,
                                                  ushort4* __restrict__ y_hi) {
    const int kl = threadIdx.x & 63;
    const int jg = threadIdx.x >> 6;          // 0..3
    const int k4 = blockIdx.x * 64 + kl;      // float4 index, 0..255
    const int b  = blockIdx.y;                // 0..15 -> pair (b, 31-b)
    const int rb = (BATCH - 1) - b;
    const int o  = blockIdx.z * 4 + jg;       // 0..63

    f32x4 accb = (f32x4){0.f, 0.f, 0.f, 0.f};
    f32x4 accr = (f32x4){0.f, 0.f, 0.f, 0.f};

#pragma unroll 4
    for (int i = 0; i < 32; ++i) {
        const int mi = 63 - i;
        f32x4 xai = xh[(size_t)(b  * CIN + i ) * 256 + k4];
        f32x4 xam = xh[(size_t)(b  * CIN + mi) * 256 + k4];
        f32x4 xbi = xh[(size_t)(rb * CIN + i ) * 256 + k4];
        f32x4 xbm = xh[(size_t)(rb * CIN + mi) * 256 + k4];
        f32x4 w1 = w[(size_t)(i  * COUT + o) * 256 + k4];
        f32x4 w2 = w[(size_t)(mi * COUT + o) * 256 + k4];
        f32x4 sa = xai + xam;
        f32x4 da = xai - xam;
        f32x4 sb = xbi + xbm;
        f32x4 db = xbi - xbm;
        f32x4 wp = w1 + w2, wm = w1 - w2;
        accb += sa * wp + db * wm;
        accr += sb * wp + da * wm;
    }

    const size_t ib = (size_t)(b  * COUT + o) * 256 + k4;
    const size_t ir = (size_t)(rb * COUT + o) * 256 + k4;
    f32x4 vb = accb * 0.5f;
    f32x4 vr = accr * 0.5f;
    __hip_bfloat16 b0 = __float2bfloat16(vb.x), b1 = __float2bfloat16(vb.y),
                   b2 = __float2bfloat16(vb.z), b3 = __float2bfloat16(vb.w);
    __hip_bfloat16 r0 = __float2bfloat16(vr.x), r1 = __float2bfloat16(vr.y),
                   r2 = __float2bfloat16(vr.z), r3 = __float2bfloat16(vr.w);
    y_hi[ib] = make_ushort4(*(unsigned short*)&b0, *(unsigned short*)&b1,
                            *(unsigned short*)&b2, *(unsigned short*)&b3);
    y_hi[ir] = make_ushort4(*(unsigned short*)&r0, *(unsigned short*)&r1,
                            *(unsigned short*)&r2, *(unsigned short*)&r3);
}

// ---------------- stage 3: iDHT MFMA GEMM, double-buffered, BK=64 ----------------
// out[r,n] = sum_k Y[r,k]*C2[k,n]; A=Y bf16 (2048x1024), B=C2T bf16 ([NPAD][1024])
// Tile 128x64, BK=64. LDS fragment-ordered 1024B blocks: block ab = group(16 rows)*2 + kchunk.
// One barrier per K-step: barrier -> stage(next buf) -> compute(cur buf).
__global__ __launch_bounds__(256) void idht_mfma(const __hip_bfloat16* __restrict__ yh,
                                                 const __hip_bfloat16* __restrict__ ch,
                                                 float* __restrict__ out) {
    __shared__ __align__(16) char sa[2][16 * 1024];   // A: 8 groups x 2 chunks
    __shared__ __align__(16) char sb[2][8 * 1024];    // B: 4 groups x 2 chunks

    const int tid  = threadIdx.x;
    const int lane = tid & 63;
    const int wave = tid >> 6;
    const int wm = wave & 1;
    const int wn = wave >> 1;
    const int rbase = blockIdx.x * 128;
    const int nbase = blockIdx.y * 64;

    const int lrow = (lane & 15) * 2048;   // global byte offset: row within 16-row group
    const int lchk = (lane >> 4) * 16;     // global byte offset within 64B half-row chunk

    const char* ga  = (const char*)yh + (size_t)rbase * 2048;
    const char* gbh = (const char*)ch + (size_t)nbase * 2048;

    f32x4 acc[4][2];
#pragma unroll
    for (int mt = 0; mt < 4; ++mt)
#pragma unroll
        for (int nt = 0; nt < 2; ++nt) acc[mt][nt] = (f32x4){0.f, 0.f, 0.f, 0.f};

    // stage K-tile k0 into buffer bi
    auto stage = [&](int bi, int k0) {
#pragma unroll
        for (int r = 0; r < 4; ++r) {
            int ab = wave + r * 4;                     // A block 0..15
            gl_lds16(ga + (size_t)(ab >> 1) * 32768 + lrow + (ab & 1) * 64 + lchk + k0 * 2,
                     sa[bi] + ab * 1024);
        }
#pragma unroll
        for (int r = 0; r < 2; ++r) {
            int bb = wave + r * 4;                     // B block 0..7
            gl_lds16(gbh + (size_t)(bb >> 1) * 32768 + lrow + (bb & 1) * 64 + lchk + k0 * 2,
                     sb[bi] + bb * 1024);
        }
    };

    stage(0, 0);
    int cur = 0;
    for (int ks = 0; ks < MODES / 64; ++ks) {
        __syncthreads();                                // buf[cur] loads complete here
        if (ks + 1 < MODES / 64) stage(1 - cur, (ks + 1) * 64);
#pragma unroll
        for (int kc = 0; kc < 2; ++kc) {
            bf16x8 a_[4], b_[2];
#pragma unroll
            for (int mt = 0; mt < 4; ++mt)
                a_[mt] = *(const bf16x8*)(sa[cur] + ((wm * 4 + mt) * 2 + kc) * 1024 + lane * 16);
#pragma unroll
            for (int nt = 0; nt < 2; ++nt)
                b_[nt] = *(const bf16x8*)(sb[cur] + ((wn * 2 + nt) * 2 + kc) * 1024 + lane * 16);
#pragma unroll
            for (int mt = 0; mt < 4; ++mt)
#pragma unroll
                for (int nt = 0; nt < 2; ++nt)
                    acc[mt][nt] = __builtin_amdgcn_mfma_f32_16x16x32_bf16(a_[mt], b_[nt], acc[mt][nt], 0, 0, 0);
        }
        cur ^= 1;
    }

    // epilogue: C/D layout col=lane&15, row=(lane>>4)*4+reg
#pragma unroll
    for (int mt = 0; mt < 4; ++mt) {
        int row = rbase + wm * 64 + mt * 16 + (lane >> 4) * 4;
#pragma unroll
        for (int nt = 0; nt < 2; ++nt) {
            int col = nbase + wn * 32 + nt * 16 + (lane & 15);
            if (col < KOUT) {
#pragma unroll
                for (int r = 0; r < 4; ++r)
                    out[(size_t)(row + r) * KOUT + col] = acc[mt][nt][r];
            }
        }
    }
}

// ---------------- launch ----------------
extern "C" void kernel_launch(void* const* d_in, const int* in_sizes, int n_in,
                              void* d_out, int out_size, void* d_ws, size_t ws_size,
                              hipStream_t stream) {
    const float* x = (const float*)d_in[0];     // (32, 64, 4096)
    const float* w = (const float*)d_in[1];     // (64, 64, 1024)
    float* out = (float*)d_out;                 // (32, 64, 2049)

    float* tw = (float*)d_ws;                                  // 4096 f32
    float* xh = tw + NFFT;                                     // 2048*1024 f32
    __hip_bfloat16* y_hi = (__hip_bfloat16*)(xh + (size_t)BATCH * CIN * MODES);
    __hip_bfloat16* c2h  = y_hi + (size_t)BATCH * COUT * MODES;

    fill_tw<<<NFFT / 256, 256, 0, stream>>>(tw);
    fill_c2t<<<(NPAD * MODES + 255) / 256, 256, 0, stream>>>(c2h);
    fht_kernel<<<BATCH * CIN, 256, 0, stream>>>(x, tw, xh);
    mix_kernel<<<dim3(4, 16, 16), 256, 0, stream>>>((const f32x4*)xh, (const f32x4*)w,
                                                    (ushort4*)y_hi);
    idht_mfma<<<dim3((BATCH * COUT) / 128, NPAD / 64), 256, 0, stream>>>(y_hi, c2h, out);
}

// Round 6
// 160.977 us; speedup vs baseline: 3.4025x; 1.0225x over previous
//
#include <hip/hip_runtime.h>
#include <hip/hip_bf16.h>

#define BATCH 32
#define CIN   64
#define COUT  64
#define NFFT  4096
#define MODES 1024
#define KOUT  2049   // N/2 + 1
#define NPAD  2176   // KOUT padded up to multiple of 64

typedef __bf16 bf16x8 __attribute__((ext_vector_type(8)));
typedef float  f32x4  __attribute__((ext_vector_type(4)));

#define AS1 __attribute__((address_space(1)))
#define AS3 __attribute__((address_space(3)))

static __device__ __forceinline__ void gl_lds16(const void* g, void* l) {
    __builtin_amdgcn_global_load_lds((const AS1 void*)g, (AS3 void*)l, 16, 0, 0);
}

// radix-4 butterfly (two fused radix-2 stages of the reference recursion)
static __device__ __forceinline__ void bfly4(float eA, float eB, float oA, float oB,
                                             float t, float c0, float c1,
                                             float& w0, float& w1, float& w2, float& w3) {
    float PA = fmaf(t, oA, eA), MA = fmaf(-t, oA, eA);
    float PB = fmaf(t, oB, eB), MB = fmaf(-t, oB, eB);
    w0 = fmaf(c0, PB, PA);
    w2 = fmaf(-c0, PB, PA);
    w1 = fmaf(c1, MB, MA);
    w3 = fmaf(-c1, MB, MA);
}

// ---------------- fill kernels ----------------

// tw[h + n] = cas(pi*n/h) for h in {1,2,...,2048}, n in [0,h). tw[0] unused.
__global__ void fill_tw(float* __restrict__ tw) {
    int t = blockIdx.x * blockDim.x + threadIdx.x;
    if (t >= NFFT) return;
    if (t == 0) { tw[0] = 1.0f; return; }
    int h = 1 << (31 - __clz(t));
    int n = t - h;
    float ang = 3.14159265358979323846f * (float)n / (float)h;
    tw[t] = cosf(ang) + sinf(ang);
}

// c2t[n*1024 + k] = cas(2*pi*(k*n mod KOUT)/KOUT)/KOUT, transposed+padded, plain bf16
__global__ void fill_c2t(__hip_bfloat16* __restrict__ hi) {
    int idx = blockIdx.x * blockDim.x + threadIdx.x;
    if (idx >= NPAD * MODES) return;
    int n = idx >> 10;
    int k = idx & 1023;
    float v = 0.0f;
    if (n < KOUT) {
        int m = (k * n) % KOUT;   // max ~2.1M, fits int32
        float ang = 6.28318530717958647692f * (float)m / (float)KOUT;
        v = (cosf(ang) + sinf(ang)) * (1.0f / (float)KOUT);
    }
    hi[idx] = __float2bfloat16(v);
}

// ---------------- stage 1: recursive "FHT", register radix-16 (4 stages/phase, 3 phases) ----------------
// Thread-local fusion of the verified radix-4 Stockham passes:
//  phase 1 (p=0,1): thread t owns positions t+256a+1024c; p=0 twiddles all 1.
//  phase 2 (p=2,3): thread (kap2=t>>4, gp=t&15) reads 256*kap2+gp+16a+64c.
//  phase 3 (p=4,5): thread k reads contiguous 16k+j; only c''=0 output kept.
// LDS exchanges use swizzle addr = p + (p>>4): writes <=3-way, reads 2-way (free).
__global__ __launch_bounds__(256) void fht_kernel(const float* __restrict__ x,
                                                  const float* __restrict__ tw,
                                                  float* __restrict__ xh) {
    __shared__ float ldsA[4352];
    __shared__ float ldsB[4352];
    const int t = threadIdx.x;
    const int row = blockIdx.x;
    const float* xr = x + (size_t)row * NFFT;

    // ---- phase 1: stages 0-3 ----
    float r[4][4];
#pragma unroll
    for (int a = 0; a < 4; ++a)
#pragma unroll
        for (int c = 0; c < 4; ++c)
            r[a][c] = xr[t + 256 * a + 1024 * c];

    float o1[4][4];
#pragma unroll
    for (int a = 0; a < 4; ++a) {     // p=0: kap=0, twiddles cas(0)=cas(pi/2)=1
        float PA = r[a][0] + r[a][2], MA = r[a][0] - r[a][2];
        float PB = r[a][1] + r[a][3], MB = r[a][1] - r[a][3];
        o1[a][0] = PA + PB;
        o1[a][2] = PA - PB;
        o1[a][1] = MA + MB;
        o1[a][3] = MA - MB;
    }
    float o2[4][4];                   // p=1: unit kap inputs o1[c][kap]
#pragma unroll
    for (int kap = 0; kap < 4; ++kap) {
        float tt = tw[4 + kap], c0 = tw[8 + kap], c1 = tw[12 + kap];
        bfly4(o1[0][kap], o1[1][kap], o1[2][kap], o1[3][kap], tt, c0, c1,
              o2[kap][0], o2[kap][1], o2[kap][2], o2[kap][3]);
    }
#pragma unroll
    for (int kap = 0; kap < 4; ++kap)
#pragma unroll
        for (int c = 0; c < 4; ++c) {
            int p = t + 256 * kap + 1024 * c;
            ldsA[p + (p >> 4)] = o2[kap][c];
        }
    __syncthreads();

    // ---- phase 2: stages 4-7 ----
    const int kap2 = t >> 4, gp = t & 15;
    float r2[4][4];
#pragma unroll
    for (int a = 0; a < 4; ++a)
#pragma unroll
        for (int c = 0; c < 4; ++c) {
            int p = 256 * kap2 + gp + 16 * a + 64 * c;
            r2[a][c] = ldsA[p + (p >> 4)];
        }
    float o3[4][4];
    {
        float tt = tw[16 + kap2], c0 = tw[32 + kap2], c1 = tw[48 + kap2];
#pragma unroll
        for (int a = 0; a < 4; ++a)   // p=2: unit a
            bfly4(r2[a][0], r2[a][1], r2[a][2], r2[a][3], tt, c0, c1,
                  o3[a][0], o3[a][1], o3[a][2], o3[a][3]);
    }
    float o4[4][4];                   // p=3: unit c inputs o3[c'][c]
#pragma unroll
    for (int c = 0; c < 4; ++c) {
        int kap3 = kap2 + 16 * c;
        float tt = tw[64 + kap3], c0 = tw[128 + kap3], c1 = tw[192 + kap3];
        bfly4(o3[0][c], o3[1][c], o3[2][c], o3[3][c], tt, c0, c1,
              o4[c][0], o4[c][1], o4[c][2], o4[c][3]);
    }
#pragma unroll
    for (int c = 0; c < 4; ++c)
#pragma unroll
        for (int cc = 0; cc < 4; ++cc) {
            int p = t + 256 * c + 1024 * cc;   // gp+16*kap2 == t
            ldsB[p + (p >> 4)] = o4[c][cc];
        }
    __syncthreads();

    // ---- phase 3: stages 8-11 ----
    float r3[4][4];
#pragma unroll
    for (int g = 0; g < 4; ++g)
#pragma unroll
        for (int c = 0; c < 4; ++c) {
            int p = 16 * t + g + 4 * c;
            r3[g][c] = ldsB[p + (p >> 4)];
        }
    float o5[4][4];
    {
        float tt = tw[256 + t], c0 = tw[512 + t], c1 = tw[768 + t];
#pragma unroll
        for (int g = 0; g < 4; ++g)   // p=4: unit g
            bfly4(r3[g][0], r3[g][1], r3[g][2], r3[g][3], tt, c0, c1,
                  o5[g][0], o5[g][1], o5[g][2], o5[g][3]);
    }
    // p=5: unit c inputs o5[c'][c]; keep only c''=0 output (positions < 1024)
    float* xo = xh + (size_t)row * MODES;
#pragma unroll
    for (int c = 0; c < 4; ++c) {
        float tt = tw[1024 + t + 256 * c];
        float c0 = tw[2048 + t + 256 * c];
        float PA = fmaf(tt, o5[2][c], o5[0][c]);
        float PB = fmaf(tt, o5[3][c], o5[1][c]);
        xo[t + 256 * c] = fmaf(c0, PB, PA);
    }
}

// ---------------- stage 2: channel mix -> Y as plain bf16 ----------------
// Thread: 4 k (float4) x 1 o x 2 b (pair b,31-b). Grid (kt=4, b=16, oz=16).
__global__ __launch_bounds__(256) void mix_kernel(const f32x4* __restrict__ xh,
                                                  const f32x4* __restrict__ w,
                                                  ushort4* __restrict__ y_hi) {
    const int kl = threadIdx.x & 63;
    const int jg = threadIdx.x >> 6;          // 0..3
    const int k4 = blockIdx.x * 64 + kl;      // float4 index, 0..255
    const int b  = blockIdx.y;                // 0..15 -> pair (b, 31-b)
    const int rb = (BATCH - 1) - b;
    const int o  = blockIdx.z * 4 + jg;       // 0..63

    f32x4 accb = (f32x4){0.f, 0.f, 0.f, 0.f};
    f32x4 accr = (f32x4){0.f, 0.f, 0.f, 0.f};

#pragma unroll 4
    for (int i = 0; i < 32; ++i) {
        const int mi = 63 - i;
        f32x4 xai = xh[(size_t)(b  * CIN + i ) * 256 + k4];
        f32x4 xam = xh[(size_t)(b  * CIN + mi) * 256 + k4];
        f32x4 xbi = xh[(size_t)(rb * CIN + i ) * 256 + k4];
        f32x4 xbm = xh[(size_t)(rb * CIN + mi) * 256 + k4];
        f32x4 w1 = w[(size_t)(i  * COUT + o) * 256 + k4];
        f32x4 w2 = w[(size_t)(mi * COUT + o) * 256 + k4];
        f32x4 sa = xai + xam;
        f32x4 da = xai - xam;
        f32x4 sb = xbi + xbm;
        f32x4 db = xbi - xbm;
        f32x4 wp = w1 + w2, wm = w1 - w2;
        accb += sa * wp + db * wm;
        accr += sb * wp + da * wm;
    }

    const size_t ib = (size_t)(b  * COUT + o) * 256 + k4;
    const size_t ir = (size_t)(rb * COUT + o) * 256 + k4;
    f32x4 vb = accb * 0.5f;
    f32x4 vr = accr * 0.5f;
    __hip_bfloat16 b0 = __float2bfloat16(vb.x), b1 = __float2bfloat16(vb.y),
                   b2 = __float2bfloat16(vb.z), b3 = __float2bfloat16(vb.w);
    __hip_bfloat16 r0 = __float2bfloat16(vr.x), r1 = __float2bfloat16(vr.y),
                   r2 = __float2bfloat16(vr.z), r3 = __float2bfloat16(vr.w);
    y_hi[ib] = make_ushort4(*(unsigned short*)&b0, *(unsigned short*)&b1,
                            *(unsigned short*)&b2, *(unsigned short*)&b3);
    y_hi[ir] = make_ushort4(*(unsigned short*)&r0, *(unsigned short*)&r1,
                            *(unsigned short*)&r2, *(unsigned short*)&r3);
}

// ---------------- stage 3: iDHT MFMA GEMM, double-buffered, BK=32, 24 KB LDS ----------------
// out[r,n] = sum_k Y[r,k]*C2[k,n]; A=Y bf16 (2048x1024), B=C2T bf16 ([NPAD][1024])
// Tile 128x64. LDS fragment-ordered 1024B groups (16 rows x 32 k); lane slot = lane*16.
// Prefetch next K-tile right after the barrier; loads fly during MFMA of current tile.
__global__ __launch_bounds__(256) void idht_mfma(const __hip_bfloat16* __restrict__ yh,
                                                 const __hip_bfloat16* __restrict__ ch,
                                                 float* __restrict__ out) {
    __shared__ __align__(16) char sa[2][8 * 1024];   // A: 8 groups
    __shared__ __align__(16) char sb[2][4 * 1024];   // B: 4 groups

    const int tid  = threadIdx.x;
    const int lane = tid & 63;
    const int wave = tid >> 6;
    const int wm = wave & 1;
    const int wn = wave >> 1;
    const int rbase = blockIdx.x * 128;
    const int nbase = blockIdx.y * 64;

    const int lrow = (lane & 15) * 2048;   // global byte offset: row within 16-row group
    const int lchk = (lane >> 4) * 16;     // global byte offset: 16B k-chunk within 64B row

    const char* ga  = (const char*)yh + (size_t)rbase * 2048;
    const char* gbh = (const char*)ch + (size_t)nbase * 2048;

    f32x4 acc[4][2];
#pragma unroll
    for (int mt = 0; mt < 4; ++mt)
#pragma unroll
        for (int nt = 0; nt < 2; ++nt) acc[mt][nt] = (f32x4){0.f, 0.f, 0.f, 0.f};

    auto stage = [&](int bi, int k0) {
#pragma unroll
        for (int r = 0; r < 2; ++r) {
            int g = wave + r * 4;          // A group 0..7
            gl_lds16(ga + (size_t)(g * 16) * 2048 + lrow + lchk + k0 * 2,
                     sa[bi] + g * 1024);
        }
        gl_lds16(gbh + (size_t)(wave * 16) * 2048 + lrow + lchk + k0 * 2,
                 sb[bi] + wave * 1024);
    };

    stage(0, 0);
    int cur = 0;
    for (int ks = 0; ks < MODES / 32; ++ks) {
        __syncthreads();                   // buf[cur] staged; prior reads of cur^1 done
        if (ks + 1 < MODES / 32) stage(cur ^ 1, (ks + 1) * 32);
        bf16x8 a_[4], b_[2];
#pragma unroll
        for (int mt = 0; mt < 4; ++mt)
            a_[mt] = *(const bf16x8*)(sa[cur] + (wm * 4 + mt) * 1024 + lane * 16);
#pragma unroll
        for (int nt = 0; nt < 2; ++nt)
            b_[nt] = *(const bf16x8*)(sb[cur] + (wn * 2 + nt) * 1024 + lane * 16);
#pragma unroll
        for (int mt = 0; mt < 4; ++mt)
#pragma unroll
            for (int nt = 0; nt < 2; ++nt)
                acc[mt][nt] = __builtin_amdgcn_mfma_f32_16x16x32_bf16(a_[mt], b_[nt], acc[mt][nt], 0, 0, 0);
        cur ^= 1;
    }

    // epilogue: C/D layout col=lane&15, row=(lane>>4)*4+reg
#pragma unroll
    for (int mt = 0; mt < 4; ++mt) {
        int row = rbase + wm * 64 + mt * 16 + (lane >> 4) * 4;
#pragma unroll
        for (int nt = 0; nt < 2; ++nt) {
            int col = nbase + wn * 32 + nt * 16 + (lane & 15);
            if (col < KOUT) {
#pragma unroll
                for (int r = 0; r < 4; ++r)
                    out[(size_t)(row + r) * KOUT + col] = acc[mt][nt][r];
            }
        }
    }
}

// ---------------- launch ----------------
extern "C" void kernel_launch(void* const* d_in, const int* in_sizes, int n_in,
                              void* d_out, int out_size, void* d_ws, size_t ws_size,
                              hipStream_t stream) {
    const float* x = (const float*)d_in[0];     // (32, 64, 4096)
    const float* w = (const float*)d_in[1];     // (64, 64, 1024)
    float* out = (float*)d_out;                 // (32, 64, 2049)

    float* tw = (float*)d_ws;                                  // 4096 f32
    float* xh = tw + NFFT;                                     // 2048*1024 f32
    __hip_bfloat16* y_hi = (__hip_bfloat16*)(xh + (size_t)BATCH * CIN * MODES);
    __hip_bfloat16* c2h  = y_hi + (size_t)BATCH * COUT * MODES;

    fill_tw<<<NFFT / 256, 256, 0, stream>>>(tw);
    fill_c2t<<<(NPAD * MODES + 255) / 256, 256, 0, stream>>>(c2h);
    fht_kernel<<<BATCH * CIN, 256, 0, stream>>>(x, tw, xh);
    mix_kernel<<<dim3(4, 16, 16), 256, 0, stream>>>((const f32x4*)xh, (const f32x4*)w,
                                                    (ushort4*)y_hi);
    idht_mfma<<<dim3((BATCH * COUT) / 128, NPAD / 64), 256, 0, stream>>>(y_hi, c2h, out);
}

// Round 7
// 153.987 us; speedup vs baseline: 3.5569x; 1.0454x over previous
//
#include <hip/hip_runtime.h>
#include <hip/hip_bf16.h>

#define BATCH 32
#define CIN   64
#define COUT  64
#define NFFT  4096
#define MODES 1024
#define KOUT  2049   // N/2 + 1
#define NPAD  2112   // 33 tiles of 64 cols (2112 >= 2049)

typedef __bf16 bf16x8 __attribute__((ext_vector_type(8)));
typedef float  f32x4  __attribute__((ext_vector_type(4)));

#define AS1 __attribute__((address_space(1)))
#define AS3 __attribute__((address_space(3)))

static __device__ __forceinline__ void gl_lds16(const void* g, void* l) {
    __builtin_amdgcn_global_load_lds((const AS1 void*)g, (AS3 void*)l, 16, 0, 0);
}

// radix-4 butterfly (two fused radix-2 stages of the reference recursion)
static __device__ __forceinline__ void bfly4(float eA, float eB, float oA, float oB,
                                             float t, float c0, float c1,
                                             float& w0, float& w1, float& w2, float& w3) {
    float PA = fmaf(t, oA, eA), MA = fmaf(-t, oA, eA);
    float PB = fmaf(t, oB, eB), MB = fmaf(-t, oB, eB);
    w0 = fmaf(c0, PB, PA);
    w2 = fmaf(-c0, PB, PA);
    w1 = fmaf(c1, MB, MA);
    w3 = fmaf(-c1, MB, MA);
}

// ---------------- fill: tw table + C2^T in MFMA-fragment order, one dispatch ----------------
// C2 fragment layout: element (n,k) lives at 16B-chunk ((n>>4)*32 + (k>>5))*64 + ((k>>3)&3)*16 + (n&15),
// byte offset (k&7)*2 within the chunk. A wave reading chunks base+lane gets exactly the
// B-frag for col-group n>>4, k-block k>>5 (col=lane&15, k=(lane>>4)*8+j).
#define NCHUNK ((NPAD / 16) * (MODES / 32) * 64)   // 132*32*64 = 270336

__global__ void fill_tables(float* __restrict__ tw, __hip_bfloat16* __restrict__ c2f) {
    int gid = blockIdx.x * 256 + threadIdx.x;
    if (gid < NCHUNK) {
        int nl  = gid & 15;
        int kc  = (gid >> 4) & 3;
        int blk = gid >> 6;
        int kb  = blk & 31;
        int gn  = blk >> 5;
        int n = gn * 16 + nl;
        int kbase = kb * 32 + kc * 8;
        unsigned short v8[8];
        if (n < KOUT) {
#pragma unroll
            for (int j = 0; j < 8; ++j) {
                int k = kbase + j;
                int m = (k * n) % KOUT;
                float ang = 6.28318530717958647692f * (float)m / (float)KOUT;
                float v = (cosf(ang) + sinf(ang)) * (1.0f / (float)KOUT);
                __hip_bfloat16 h = __float2bfloat16(v);
                v8[j] = *(unsigned short*)&h;
            }
        } else {
#pragma unroll
            for (int j = 0; j < 8; ++j) v8[j] = 0;
        }
        *(ushort4*)((char*)c2f + (size_t)gid * 16)     = make_ushort4(v8[0], v8[1], v8[2], v8[3]);
        *(ushort4*)((char*)c2f + (size_t)gid * 16 + 8) = make_ushort4(v8[4], v8[5], v8[6], v8[7]);
    } else {
        int t = gid - NCHUNK;
        if (t < NFFT) {
            if (t == 0) { tw[0] = 1.0f; return; }
            int h = 1 << (31 - __clz(t));
            int n = t - h;
            float ang = 3.14159265358979323846f * (float)n / (float)h;
            tw[t] = cosf(ang) + sinf(ang);
        }
    }
}

// ---------------- stage 1: recursive "FHT", register radix-16 (3 phases) ----------------
__global__ __launch_bounds__(256) void fht_kernel(const float* __restrict__ x,
                                                  const float* __restrict__ tw,
                                                  float* __restrict__ xh) {
    __shared__ float ldsA[4352];
    __shared__ float ldsB[4352];
    const int t = threadIdx.x;
    const int row = blockIdx.x;
    const float* xr = x + (size_t)row * NFFT;

    // ---- phase 1: stages 0-3 ----
    float r[4][4];
#pragma unroll
    for (int a = 0; a < 4; ++a)
#pragma unroll
        for (int c = 0; c < 4; ++c)
            r[a][c] = xr[t + 256 * a + 1024 * c];

    float o1[4][4];
#pragma unroll
    for (int a = 0; a < 4; ++a) {     // p=0: twiddles all 1
        float PA = r[a][0] + r[a][2], MA = r[a][0] - r[a][2];
        float PB = r[a][1] + r[a][3], MB = r[a][1] - r[a][3];
        o1[a][0] = PA + PB;
        o1[a][2] = PA - PB;
        o1[a][1] = MA + MB;
        o1[a][3] = MA - MB;
    }
    float o2[4][4];
#pragma unroll
    for (int kap = 0; kap < 4; ++kap) {
        float tt = tw[4 + kap], c0 = tw[8 + kap], c1 = tw[12 + kap];
        bfly4(o1[0][kap], o1[1][kap], o1[2][kap], o1[3][kap], tt, c0, c1,
              o2[kap][0], o2[kap][1], o2[kap][2], o2[kap][3]);
    }
#pragma unroll
    for (int kap = 0; kap < 4; ++kap)
#pragma unroll
        for (int c = 0; c < 4; ++c) {
            int p = t + 256 * kap + 1024 * c;
            ldsA[p + (p >> 4)] = o2[kap][c];
        }
    __syncthreads();

    // ---- phase 2: stages 4-7 ----
    const int kap2 = t >> 4, gp = t & 15;
    float r2[4][4];
#pragma unroll
    for (int a = 0; a < 4; ++a)
#pragma unroll
        for (int c = 0; c < 4; ++c) {
            int p = 256 * kap2 + gp + 16 * a + 64 * c;
            r2[a][c] = ldsA[p + (p >> 4)];
        }
    float o3[4][4];
    {
        float tt = tw[16 + kap2], c0 = tw[32 + kap2], c1 = tw[48 + kap2];
#pragma unroll
        for (int a = 0; a < 4; ++a)
            bfly4(r2[a][0], r2[a][1], r2[a][2], r2[a][3], tt, c0, c1,
                  o3[a][0], o3[a][1], o3[a][2], o3[a][3]);
    }
    float o4[4][4];
#pragma unroll
    for (int c = 0; c < 4; ++c) {
        int kap3 = kap2 + 16 * c;
        float tt = tw[64 + kap3], c0 = tw[128 + kap3], c1 = tw[192 + kap3];
        bfly4(o3[0][c], o3[1][c], o3[2][c], o3[3][c], tt, c0, c1,
              o4[c][0], o4[c][1], o4[c][2], o4[c][3]);
    }
#pragma unroll
    for (int c = 0; c < 4; ++c)
#pragma unroll
        for (int cc = 0; cc < 4; ++cc) {
            int p = t + 256 * c + 1024 * cc;
            ldsB[p + (p >> 4)] = o4[c][cc];
        }
    __syncthreads();

    // ---- phase 3: stages 8-11 ----
    float r3[4][4];
#pragma unroll
    for (int g = 0; g < 4; ++g)
#pragma unroll
        for (int c = 0; c < 4; ++c) {
            int p = 16 * t + g + 4 * c;
            r3[g][c] = ldsB[p + (p >> 4)];
        }
    float o5[4][4];
    {
        float tt = tw[256 + t], c0 = tw[512 + t], c1 = tw[768 + t];
#pragma unroll
        for (int g = 0; g < 4; ++g)
            bfly4(r3[g][0], r3[g][1], r3[g][2], r3[g][3], tt, c0, c1,
                  o5[g][0], o5[g][1], o5[g][2], o5[g][3]);
    }
    float* xo = xh + (size_t)row * MODES;
#pragma unroll
    for (int c = 0; c < 4; ++c) {
        float tt = tw[1024 + t + 256 * c];
        float c0 = tw[2048 + t + 256 * c];
        float PA = fmaf(tt, o5[2][c], o5[0][c]);
        float PB = fmaf(tt, o5[3][c], o5[1][c]);
        xo[t + 256 * c] = fmaf(c0, PB, PA);
    }
}

// ---------------- stage 2: channel mix -> Y as plain bf16 (row-major) ----------------
__global__ __launch_bounds__(256) void mix_kernel(const f32x4* __restrict__ xh,
                                                  const f32x4* __restrict__ w,
                                                  ushort4* __restrict__ y_hi) {
    const int kl = threadIdx.x & 63;
    const int jg = threadIdx.x >> 6;          // 0..3
    const int k4 = blockIdx.x * 64 + kl;      // float4 index, 0..255
    const int b  = blockIdx.y;                // 0..15 -> pair (b, 31-b)
    const int rb = (BATCH - 1) - b;
    const int o  = blockIdx.z * 4 + jg;       // 0..63

    f32x4 accb = (f32x4){0.f, 0.f, 0.f, 0.f};
    f32x4 accr = (f32x4){0.f, 0.f, 0.f, 0.f};

#pragma unroll 4
    for (int i = 0; i < 32; ++i) {
        const int mi = 63 - i;
        f32x4 xai = xh[(size_t)(b  * CIN + i ) * 256 + k4];
        f32x4 xam = xh[(size_t)(b  * CIN + mi) * 256 + k4];
        f32x4 xbi = xh[(size_t)(rb * CIN + i ) * 256 + k4];
        f32x4 xbm = xh[(size_t)(rb * CIN + mi) * 256 + k4];
        f32x4 w1 = w[(size_t)(i  * COUT + o) * 256 + k4];
        f32x4 w2 = w[(size_t)(mi * COUT + o) * 256 + k4];
        f32x4 sa = xai + xam;
        f32x4 da = xai - xam;
        f32x4 sb = xbi + xbm;
        f32x4 db = xbi - xbm;
        f32x4 wp = w1 + w2, wm = w1 - w2;
        accb += sa * wp + db * wm;
        accr += sb * wp + da * wm;
    }

    const size_t ib = (size_t)(b  * COUT + o) * 256 + k4;
    const size_t ir = (size_t)(rb * COUT + o) * 256 + k4;
    f32x4 vb = accb * 0.5f;
    f32x4 vr = accr * 0.5f;
    __hip_bfloat16 b0 = __float2bfloat16(vb.x), b1 = __float2bfloat16(vb.y),
                   b2 = __float2bfloat16(vb.z), b3 = __float2bfloat16(vb.w);
    __hip_bfloat16 r0 = __float2bfloat16(vr.x), r1 = __float2bfloat16(vr.y),
                   r2 = __float2bfloat16(vr.z), r3 = __float2bfloat16(vr.w);
    y_hi[ib] = make_ushort4(*(unsigned short*)&b0, *(unsigned short*)&b1,
                            *(unsigned short*)&b2, *(unsigned short*)&b3);
    y_hi[ir] = make_ushort4(*(unsigned short*)&r0, *(unsigned short*)&r1,
                            *(unsigned short*)&r2, *(unsigned short*)&r3);
}

// ---------------- stage 3: iDHT MFMA GEMM ----------------
// 64x64 tile, 128 threads (2 waves), BK=32, grid 32x33 = 1056 blocks.
// A (Y, row-major) LDS-staged double-buffered (8 KB total); B (C2 frag-order) loaded
// straight from global to VGPR frags, software-pipelined one K-step ahead (no barrier dep).
__global__ __launch_bounds__(128) void idht_mfma(const __hip_bfloat16* __restrict__ yh,
                                                 const __hip_bfloat16* __restrict__ c2f,
                                                 float* __restrict__ out) {
    __shared__ __align__(16) char sa[2][4 * 1024];   // A: 4 groups of (16 rows x 32 k)

    const int tid  = threadIdx.x;
    const int lane = tid & 63;
    const int wave = tid >> 6;                // 0..1
    const int rbase = blockIdx.x * 64;
    const int gn0   = blockIdx.y * 4;         // first col-group; nbase = gn0*16
    const int nbase = gn0 * 16;

    const int lrow = (lane & 15) * 2048;      // A: row-in-group byte offset (row-major, 2048 B/row)
    const int lchk = (lane >> 4) * 16;        // A: 16B k-chunk within 64B

    const char* ga = (const char*)yh + (size_t)rbase * 2048;
    const char* gb = (const char*)c2f;

    f32x4 acc[2][4];
#pragma unroll
    for (int mt = 0; mt < 2; ++mt)
#pragma unroll
        for (int nt = 0; nt < 4; ++nt) acc[mt][nt] = (f32x4){0.f, 0.f, 0.f, 0.f};

    auto stageA = [&](int bi, int k0) {
#pragma unroll
        for (int r = 0; r < 2; ++r) {
            int g = wave * 2 + r;             // group 0..3
            gl_lds16(ga + (size_t)(g * 16) * 2048 + lrow + lchk + k0 * 2,
                     sa[bi] + g * 1024);
        }
    };
    auto loadB = [&](int ks, bf16x8* b_) {
#pragma unroll
        for (int nt = 0; nt < 4; ++nt) {
            size_t ch = ((size_t)(gn0 + nt) * 32 + ks) * 64 + lane;
            b_[nt] = *(const bf16x8*)(gb + ch * 16);
        }
    };

    stageA(0, 0);
    bf16x8 bcur[4];
    loadB(0, bcur);
    int cur = 0;
    for (int ks = 0; ks < MODES / 32; ++ks) {
        __syncthreads();                      // sa[cur] staged; prior reads of sa[cur^1] done
        if (ks + 1 < MODES / 32) stageA(cur ^ 1, (ks + 1) * 32);
        bf16x8 bnext[4];
        int kn = (ks + 1 < MODES / 32) ? ks + 1 : ks;   // clamped prefetch (uniform)
        loadB(kn, bnext);
        bf16x8 a_[2];
#pragma unroll
        for (int mt = 0; mt < 2; ++mt)
            a_[mt] = *(const bf16x8*)(sa[cur] + (wave * 2 + mt) * 1024 + lane * 16);
#pragma unroll
        for (int mt = 0; mt < 2; ++mt)
#pragma unroll
            for (int nt = 0; nt < 4; ++nt)
                acc[mt][nt] = __builtin_amdgcn_mfma_f32_16x16x32_bf16(a_[mt], bcur[nt], acc[mt][nt], 0, 0, 0);
#pragma unroll
        for (int nt = 0; nt < 4; ++nt) bcur[nt] = bnext[nt];
        cur ^= 1;
    }

    // epilogue: C/D layout col=lane&15, row=(lane>>4)*4+reg
#pragma unroll
    for (int mt = 0; mt < 2; ++mt) {
        int row = rbase + wave * 32 + mt * 16 + (lane >> 4) * 4;
#pragma unroll
        for (int nt = 0; nt < 4; ++nt) {
            int col = nbase + nt * 16 + (lane & 15);
            if (col < KOUT) {
#pragma unroll
                for (int r = 0; r < 4; ++r)
                    out[(size_t)(row + r) * KOUT + col] = acc[mt][nt][r];
            }
        }
    }
}

// ---------------- launch ----------------
extern "C" void kernel_launch(void* const* d_in, const int* in_sizes, int n_in,
                              void* d_out, int out_size, void* d_ws, size_t ws_size,
                              hipStream_t stream) {
    const float* x = (const float*)d_in[0];     // (32, 64, 4096)
    const float* w = (const float*)d_in[1];     // (64, 64, 1024)
    float* out = (float*)d_out;                 // (32, 64, 2049)

    float* tw = (float*)d_ws;                                  // 4096 f32
    float* xh = tw + NFFT;                                     // 2048*1024 f32
    __hip_bfloat16* y_hi = (__hip_bfloat16*)(xh + (size_t)BATCH * CIN * MODES);
    __hip_bfloat16* c2f  = y_hi + (size_t)BATCH * COUT * MODES;

    fill_tables<<<(NCHUNK + NFFT + 255) / 256, 256, 0, stream>>>(tw, c2f);
    fht_kernel<<<BATCH * CIN, 256, 0, stream>>>(x, tw, xh);
    mix_kernel<<<dim3(4, 16, 16), 256, 0, stream>>>((const f32x4*)xh, (const f32x4*)w,
                                                    (ushort4*)y_hi);
    idht_mfma<<<dim3((BATCH * COUT) / 64, NPAD / 64), 128, 0, stream>>>(y_hi, c2f, out);
}